// Round 10
// baseline (3417.485 us; speedup 1.0000x reference)
//
#include <hip/hip_runtime.h>
#include <stdint.h>

// ---------------------------------------------------------------------------
// TMA head on MI355X. Round 10: fp32 partials restored (bf16 partials broke
// absolute-error budget on the large-valued final conv). gemm256 keeps BK=32 /
// 64KB LDS (2 blocks/CU, launch_bounds(512,4)). Tiered ws layout: if ws fits
// 128MB partials, z doubles (all heavy grids = 512 blocks); else round-7 z.
// ---------------------------------------------------------------------------

typedef short bf16x8 __attribute__((ext_vector_type(8)));
typedef float f32x4  __attribute__((ext_vector_type(4)));
typedef unsigned short u16x4 __attribute__((ext_vector_type(4)));

__device__ __forceinline__ unsigned short f2bf(float f) {
  union { float f; unsigned u; } x; x.f = f;
  unsigned r = x.u + 0x7FFFu + ((x.u >> 16) & 1u);   // RNE
  return (unsigned short)(r >> 16);
}

typedef const __attribute__((address_space(1))) char* as1cp;
typedef __attribute__((address_space(3))) char* as3p;

__device__ __forceinline__ void gl_lds16(const char* g, char* l) {
  __builtin_amdgcn_global_load_lds((as1cp)g, (as3p)l, 16, 0, 0);
}

enum { G_PART = 0, G_CL = 1, G_EXPSUM = 2 };

// ===========================================================================
// gemm256: 256x256 tile, BK=32, 512 threads (8 waves: 2 m-rows x 4 n-cols),
// 64KB LDS -> 2 blocks/CU (VGPR capped via launch_bounds(512,4)).
// Per 32-k phase: {12 ds_read, stage next (4 gl_lds), 32 MFMA (setprio),
// vmcnt(4), barrier} -- counted wait never drains in steady state.
// Swizzled LDS panels (0 bank conflicts measured); XCD block swizzle.
// EP: G_PART  -> fp32 partials P[z][gn][gm]
//     G_CL    -> bf16 out[gn(pos)][gm(co)] with BN(gsplit)+ReLU fused
//     G_EXPSUM-> exp() to tiled expS [gm/32][Ostride=qtot][gm&31] + rowsum
// ===========================================================================
template<int EP, bool CF, bool CONV3, bool XTILED>
__global__ __launch_bounds__(512, 4) void gemm256(
    const unsigned short* __restrict__ Wp,   // [rows][K] bf16
    const unsigned short* __restrict__ Xp,   // activations (or tiled expS)
    int K, int Kc, int Xstride, int Xcoloff, int cin_log2,
    void* __restrict__ Op, int Ostride, size_t plane,
    const float* __restrict__ g1, const float* __restrict__ b1,
    const float* __restrict__ g2, const float* __restrict__ b2, int gsplit,
    float* __restrict__ rowsum, const char* __restrict__ zp)
{
  __shared__ short Ap[2][8192];   // [buf][1024 slots * 8 shorts] = 16KB each
  __shared__ short Bp[2][8192];
  const int tid = threadIdx.x;
  const int w = tid >> 6;
  const int l = tid & 63;
  const int wm_idx = w >> 2;     // 0..1
  const int wn_idx = w & 3;      // 0..3

  // XCD-aware bijective block swizzle (nwg % 8 == 0 for all call sites)
  int bx = blockIdx.x, by = blockIdx.y;
  {
    int nwg = gridDim.x * gridDim.y;
    if ((nwg & 7) == 0) {
      int id = bx + gridDim.x * by;
      id = (id & 7) * (nwg >> 3) + (id >> 3);
      bx = id % gridDim.x;
      by = id / gridDim.x;
    }
  }
  const int n0 = bx * 256;
  const int m0 = by * 256;
  const int wrow0 = CF ? n0 : m0;
  const int xrow0 = CF ? m0 : n0;

  // staging lane constants: g = (l&7)^(l>>3), rows grow0/grow0+16
  const int g = (l & 7) ^ (l >> 3);
  const int grow0 = w * 32 + 2 * (l >> 3) + (g >> 2);
  const int gc = g & 3;

  auto srcW = [&](int grow, int k0) -> const char* {
    return (const char*)Wp +
           (((size_t)(wrow0 + grow)) * K + (size_t)(k0 + gc * 8)) * 2;
  };
  auto srcX = [&](int grow, int k0) -> const char* {
    if constexpr (XTILED) {
      return (const char*)Xp + (size_t)(k0 >> 5) * ((size_t)Xstride * 64)
             + (size_t)(xrow0 + grow) * 64 + gc * 16;
    } else if constexpr (CONV3) {
      int e = k0 >> cin_log2;
      int ci0 = k0 & ((1 << cin_log2) - 1);
      int kh = e / 3, kw = e - kh * 3;
      int dpos = (kh - 1) * 64 + (kw - 1);
      int p = xrow0 + grow;
      int hw = p & 4095;
      int h2 = (hw >> 6) + kh - 1, w2 = (hw & 63) + kw - 1;
      return ((unsigned)h2 < 64u && (unsigned)w2 < 64u)
          ? (const char*)Xp + (((size_t)(p + dpos)) * Xstride
                               + (size_t)(Xcoloff + ci0 + gc * 8)) * 2
          : zp + gc * 16;
    } else {
      return (const char*)Xp + (((size_t)(xrow0 + grow)) * Xstride
                                + (size_t)(Xcoloff + k0 + gc * 8)) * 2;
    }
  };

  // stage 32-k panels of tile at k0 into buffer b: 4 gl_lds per thread
  auto stage = [&](int b, int k0) {
#pragma unroll
    for (int j = 0; j < 2; j++) {
      int grow = grow0 + j * 16;
      const char* sm = CF ? srcX(grow, k0) : srcW(grow, k0);
      gl_lds16(sm, (char*)&Ap[b][0] + w * 2048 + j * 1024);
    }
#pragma unroll
    for (int j = 0; j < 2; j++) {
      int grow = grow0 + j * 16;
      const char* sn = CF ? srcW(grow, k0) : srcX(grow, k0);
      gl_lds16(sn, (char*)&Bp[b][0] + w * 2048 + j * 1024);
    }
  };

  auto rd = [&](const short* base, int row, int ks) -> bf16x8 {
    int R = row >> 1;
    int sp = (((row & 1) << 2) | ks) ^ (R & 7);
    return *(const bf16x8*)(base + R * 64 + sp * 8);
  };

  f32x4 acc[8][4] = {};

  const int kb = blockIdx.z * Kc;
  const int NT = Kc >> 5;

  stage(0, kb);
  asm volatile("s_waitcnt vmcnt(0)" ::: "memory");
  __builtin_amdgcn_s_barrier();

  int buf = 0;
  for (int t = 0; t < NT; ++t) {
    const bool pre = (t + 1 < NT);
    const short* Am = &Ap[buf][0];
    const short* Bm = &Bp[buf][0];
    bf16x8 af[8], bfv[4];
#pragma unroll
    for (int i = 0; i < 8; i++)
      af[i] = rd(Am, wm_idx * 128 + i * 16 + (l & 15), l >> 4);
#pragma unroll
    for (int j = 0; j < 4; j++)
      bfv[j] = rd(Bm, wn_idx * 64 + j * 16 + (l & 15), l >> 4);
    if (pre) stage(buf ^ 1, kb + (t + 1) * 32);
    __builtin_amdgcn_s_setprio(1);
#pragma unroll
    for (int i = 0; i < 8; i++)
#pragma unroll
      for (int j = 0; j < 4; j++)
        acc[i][j] = __builtin_amdgcn_mfma_f32_16x16x32_bf16(af[i], bfv[j], acc[i][j], 0, 0, 0);
    __builtin_amdgcn_s_setprio(0);
    if (pre) asm volatile("s_waitcnt vmcnt(4)" ::: "memory");
    else     asm volatile("s_waitcnt vmcnt(0)" ::: "memory");
    __builtin_amdgcn_s_barrier();
    buf ^= 1;
  }

  const int col = l & 15;
  const int rb2 = (l >> 4) << 2;

  if constexpr (EP == G_PART) {
    float* Pz = (float*)Op + (size_t)blockIdx.z * plane;
#pragma unroll
    for (int j = 0; j < 4; j++) {
      int gn = n0 + wn_idx * 64 + j * 16 + col;
#pragma unroll
      for (int i = 0; i < 8; i++) {
        int gm = m0 + wm_idx * 128 + i * 16 + rb2;
        *(f32x4*)(Pz + (size_t)gn * Ostride + gm) = acc[i][j];
      }
    }
  }
  if constexpr (EP == G_CL) {
    // out[gn(pos)][gm(co)] bf16, BN(gsplit on gm)+ReLU
#pragma unroll
    for (int i = 0; i < 8; i++) {
      int gm = m0 + wm_idx * 128 + i * 16 + rb2;
      const float* gp; const float* bp;
      if (gm < gsplit) { gp = g1 + gm; bp = b1 + gm; }
      else             { gp = g2 + (gm - gsplit); bp = b2 + (gm - gsplit); }
      float G[4], B[4];
#pragma unroll
      for (int r = 0; r < 4; r++) { G[r] = gp[r]; B[r] = bp[r]; }
#pragma unroll
      for (int j = 0; j < 4; j++) {
        int gn = n0 + wn_idx * 64 + j * 16 + col;
        f32x4 v = acc[i][j];
        u16x4 o;
#pragma unroll
        for (int r = 0; r < 4; r++) o[r] = f2bf(fmaxf(v[r] * G[r] + B[r], 0.f));
        *(u16x4*)((unsigned short*)Op + (size_t)gn * Ostride + gm) = o;
      }
    }
  }
  if constexpr (EP == G_EXPSUM) {
    // gm = kpos, gn = q; tiled expS [kpos/32][Ostride=qtot][kpos&31] + rowsum
#pragma unroll
    for (int j = 0; j < 4; j++) {
      int gn = n0 + wn_idx * 64 + j * 16 + col;   // q
      float s = 0.f;
#pragma unroll
      for (int i = 0; i < 8; i++) {
        int gm = m0 + wm_idx * 128 + i * 16 + rb2;  // kpos
        f32x4 v = acc[i][j];
        u16x4 o;
#pragma unroll
        for (int r = 0; r < 4; r++) { float e = __expf(v[r]); s += e; o[r] = f2bf(e); }
        *(u16x4*)((unsigned short*)Op + (size_t)(gm >> 5) * ((size_t)Ostride * 32)
                  + (size_t)gn * 32 + (gm & 31)) = o;
      }
      s += __shfl_xor(s, 16);
      s += __shfl_xor(s, 32);
      if (l < 16) atomicAdd(rowsum + gn, s);
    }
  }
}

enum { EP_CL_BNR = 0, EP_CF_BNR_BF16 = 1, EP_CF_BNR_F32 = 2, EP_EXPSUM = 3,
       EP_PVDIV = 4, EP_PART = 5 };

// 128x128 tile, BK=32, 256 threads (4 waves). Depth-2 pipeline. fp32 partials.
template<int EP, bool CF, bool CONV3, bool XTILED>
__global__ __launch_bounds__(256) void gemm_k(
    const unsigned short* __restrict__ Wp,
    const unsigned short* __restrict__ Xp,
    int K, int Kc, int Xstride, int Xcoloff, int cin_log2,
    void* __restrict__ Op, int Ostride, int Ocoloff, size_t plane,
    const float* __restrict__ g1, const float* __restrict__ b1,
    const float* __restrict__ g2, const float* __restrict__ b2, int gsplit,
    float* __restrict__ rowsum, const char* __restrict__ zp)
{
  __shared__ short Wt[2][128 * 32];
  __shared__ short Xt[2][128 * 32];
  const int tid = threadIdx.x;
  const int w = tid >> 6;
  const int l = tid & 63;
  const int m0 = blockIdx.y * 128;
  const int n0 = blockIdx.x * 128;
  const int wrow0 = CF ? n0 : m0;
  const int xrow0 = CF ? m0 : n0;

  const int ch0 = w, ch1 = w + 4;
  const int sr0 = ch0 * 16 + (l >> 2);
  const int sr1 = ch1 * 16 + (l >> 2);
  const int kbp = (l & 3) << 4;
  const int kbl0 = kbp ^ ((sr0 & 3) << 4);
  const int kbl1 = kbp ^ ((sr1 & 3) << 4);

  const size_t wrb = (size_t)K * 2;
  const size_t xrb = (size_t)Xstride * 2;

  const int wm = (w >> 1) * 64;
  const int wn = (w & 1) * 64;

  const int k_begin = blockIdx.z * Kc;
  const int k_end = (k_begin + Kc < K) ? (k_begin + Kc) : K;

  auto stage = [&](int b, int k0) {
    int ci0 = k0, kh = 1, kw = 1, dpos = 0;
    if (CONV3) {
      int e = k0 >> cin_log2;
      ci0 = k0 & ((1 << cin_log2) - 1);
      kh = e / 3; kw = e - kh * 3;
      dpos = (kh - 1) * 64 + (kw - 1);
    }
    char* Wl = (char*)&Wt[b][0];
    char* Xl = (char*)&Xt[b][0];
    gl_lds16((const char*)Wp + (size_t)(wrow0 + sr0) * wrb + (size_t)k0 * 2 + kbl0,
             Wl + ch0 * 1024);
    gl_lds16((const char*)Wp + (size_t)(wrow0 + sr1) * wrb + (size_t)k0 * 2 + kbl1,
             Wl + ch1 * 1024);
    const char* xs0;
    const char* xs1;
    if constexpr (XTILED) {
      size_t kslab = (size_t)(k0 >> 5) * ((size_t)Xstride * 64);
      xs0 = (const char*)Xp + kslab + (size_t)(xrow0 + sr0) * 64 + kbl0;
      xs1 = (const char*)Xp + kslab + (size_t)(xrow0 + sr1) * 64 + kbl1;
    } else if constexpr (CONV3) {
      int p = xrow0 + sr0;
      int hw = p & 4095;
      int h2 = (hw >> 6) + kh - 1, w2 = (hw & 63) + kw - 1;
      xs0 = ((unsigned)h2 < 64u && (unsigned)w2 < 64u)
          ? (const char*)Xp + (size_t)(p + dpos) * xrb + (size_t)(Xcoloff + ci0) * 2 + kbl0
          : zp + kbl0;
      p = xrow0 + sr1;
      hw = p & 4095;
      h2 = (hw >> 6) + kh - 1; w2 = (hw & 63) + kw - 1;
      xs1 = ((unsigned)h2 < 64u && (unsigned)w2 < 64u)
          ? (const char*)Xp + (size_t)(p + dpos) * xrb + (size_t)(Xcoloff + ci0) * 2 + kbl1
          : zp + kbl1;
    } else {
      xs0 = (const char*)Xp + (size_t)(xrow0 + sr0) * xrb + (size_t)(Xcoloff + k0) * 2 + kbl0;
      xs1 = (const char*)Xp + (size_t)(xrow0 + sr1) * xrb + (size_t)(Xcoloff + k0) * 2 + kbl1;
    }
    gl_lds16(xs0, Xl + ch0 * 1024);
    gl_lds16(xs1, Xl + ch1 * 1024);
  };

  f32x4 acc[4][4] = {};

  int cur = 0;
  stage(0, k_begin);
  for (int k0 = k_begin; k0 < k_end; k0 += 32) {
    if (k0 + 32 < k_end) {
      stage(cur ^ 1, k0 + 32);
      asm volatile("s_waitcnt vmcnt(4)" ::: "memory");
    } else {
      asm volatile("s_waitcnt vmcnt(0)" ::: "memory");
    }
    __builtin_amdgcn_s_barrier();

    const short* Wb = &Wt[cur][0];
    const short* Xb = &Xt[cur][0];
    const short* At = CF ? Xb : Wb;
    const short* Bt = CF ? Wb : Xb;

    bf16x8 af[4], bfv[4];
#pragma unroll
    for (int i = 0; i < 4; i++) {
      int row = wm + i * 16 + (l & 15);
      int kb = ((l >> 4) << 4) ^ ((row & 3) << 4);
      af[i] = *(const bf16x8*)(At + row * 32 + (kb >> 1));
    }
#pragma unroll
    for (int j = 0; j < 4; j++) {
      int row = wn + j * 16 + (l & 15);
      int kb = ((l >> 4) << 4) ^ ((row & 3) << 4);
      bfv[j] = *(const bf16x8*)(Bt + row * 32 + (kb >> 1));
    }
#pragma unroll
    for (int i = 0; i < 4; i++)
#pragma unroll
      for (int j = 0; j < 4; j++)
        acc[i][j] = __builtin_amdgcn_mfma_f32_16x16x32_bf16(af[i], bfv[j], acc[i][j], 0, 0, 0);

    __builtin_amdgcn_s_barrier();
    cur ^= 1;
  }

  const int col = l & 15;
  const int rb = (l >> 4) << 2;

  if constexpr (EP == EP_PART) {
    float* P = (float*)Op + (size_t)blockIdx.z * plane;
#pragma unroll
    for (int j = 0; j < 4; j++) {
      int gn = n0 + wn + j * 16 + col;
#pragma unroll
      for (int i = 0; i < 4; i++) {
        int gm = m0 + wm + i * 16 + rb;
        *(f32x4*)(P + (size_t)gn * Ostride + gm) = acc[i][j];
      }
    }
  }
  if constexpr (EP == EP_CL_BNR) {
#pragma unroll
    for (int i = 0; i < 4; i++) {
      int gm = m0 + wm + i * 16 + rb;
      const float* gp; const float* bp;
      if (gm < gsplit) { gp = g1 + gm; bp = b1 + gm; }
      else             { gp = g2 + (gm - gsplit); bp = b2 + (gm - gsplit); }
      float G[4], B[4];
#pragma unroll
      for (int r = 0; r < 4; r++) { G[r] = gp[r]; B[r] = bp[r]; }
#pragma unroll
      for (int j = 0; j < 4; j++) {
        int gn = n0 + wn + j * 16 + col;
        f32x4 v = acc[i][j];
        u16x4 o;
#pragma unroll
        for (int r = 0; r < 4; r++) o[r] = f2bf(fmaxf(v[r] * G[r] + B[r], 0.f));
        *(u16x4*)((unsigned short*)Op + (size_t)gn * Ostride + Ocoloff + gm) = o;
      }
    }
  }
  if constexpr (EP == EP_CF_BNR_BF16 || EP == EP_CF_BNR_F32) {
#pragma unroll
    for (int j = 0; j < 4; j++) {
      int gn = n0 + wn + j * 16 + col;
      float G = (gn < gsplit) ? g1[gn] : g2[gn - gsplit];
      float Bv = (gn < gsplit) ? b1[gn] : b2[gn - gsplit];
#pragma unroll
      for (int i = 0; i < 4; i++) {
        int gm = m0 + wm + i * 16 + rb;
        f32x4 v = acc[i][j];
        if constexpr (EP == EP_CF_BNR_F32) {
          f32x4 o;
#pragma unroll
          for (int r = 0; r < 4; r++) o[r] = fmaxf(v[r] * G + Bv, 0.f);
          *(f32x4*)((float*)Op + (size_t)gn * Ostride + Ocoloff + gm) = o;
        } else {
          u16x4 o;
#pragma unroll
          for (int r = 0; r < 4; r++) o[r] = f2bf(fmaxf(v[r] * G + Bv, 0.f));
          *(u16x4*)((unsigned short*)Op + (size_t)gn * Ostride + Ocoloff + gm) = o;
        }
      }
    }
  }
  if constexpr (EP == EP_EXPSUM) {
#pragma unroll
    for (int j = 0; j < 4; j++) {
      int gn = n0 + wn + j * 16 + col;   // q
      float s = 0.f;
#pragma unroll
      for (int i = 0; i < 4; i++) {
        int gm = m0 + wm + i * 16 + rb;  // kpos
        f32x4 v = acc[i][j];
        u16x4 o;
#pragma unroll
        for (int r = 0; r < 4; r++) { float e = __expf(v[r]); s += e; o[r] = f2bf(e); }
        if (gsplit)
          *(u16x4*)((unsigned short*)Op + (size_t)(gm >> 5) * ((size_t)Ostride * 32)
                    + (size_t)gn * 32 + (gm & 31)) = o;
        else
          *(u16x4*)((unsigned short*)Op + (size_t)gn * Ostride + gm) = o;
      }
      s += __shfl_xor(s, 16);
      s += __shfl_xor(s, 32);
      if (l < 16) atomicAdd(rowsum + gn, s);
    }
  }
  if constexpr (EP == EP_PVDIV) {
#pragma unroll
    for (int j = 0; j < 4; j++) {
      int gn = n0 + wn + j * 16 + col;   // q
      float inv = 1.0f / rowsum[gn];
#pragma unroll
      for (int i = 0; i < 4; i++) {
        int gm = m0 + wm + i * 16 + rb;  // c
        f32x4 v = acc[i][j];
        u16x4 o;
#pragma unroll
        for (int r = 0; r < 4; r++) o[r] = f2bf(v[r] * inv);
        *(u16x4*)((unsigned short*)Op + (size_t)gn * Ostride + Ocoloff + gm) = o;
      }
    }
  }
}

// ---- split-K reduce: sum Z fp32 planes, apply epilogue ----
enum { RED_BNR_BF16 = 0, RED_PVDIV = 1, RED_BNR_F32 = 2, RED_BNR_BF16_N = 3 };

template<int MODE>
__global__ __launch_bounds__(256) void reduce_k(
    const float* __restrict__ P, int Z, size_t plane, int Cdim,
    void* __restrict__ out, int Ostride, int Ocoloff,
    const float* __restrict__ g1, const float* __restrict__ b1,
    const float* __restrict__ g2, const float* __restrict__ b2, int gsplit,
    const float* __restrict__ rowsum, int total4)
{
  int t = blockIdx.x * 256 + threadIdx.x;
  if (t >= total4) return;
  size_t base = (size_t)t * 4;
  int n = (int)(base / (size_t)Cdim);
  int c = (int)(base % (size_t)Cdim);
  f32x4 s = *(const f32x4*)(P + base);
  for (int z = 1; z < Z; z++) {
    f32x4 v = *(const f32x4*)(P + (size_t)z * plane + base);
    s += v;
  }
  if constexpr (MODE == RED_BNR_BF16) {
    u16x4 o;
#pragma unroll
    for (int r = 0; r < 4; r++) {
      int ch = c + r;
      float G = (ch < gsplit) ? g1[ch] : g2[ch - gsplit];
      float B = (ch < gsplit) ? b1[ch] : b2[ch - gsplit];
      o[r] = f2bf(fmaxf(s[r] * G + B, 0.f));
    }
    *(u16x4*)((unsigned short*)out + (size_t)n * Ostride + Ocoloff + c) = o;
  }
  if constexpr (MODE == RED_BNR_BF16_N) {
    float G = g1[n], B = b1[n];
    u16x4 o;
#pragma unroll
    for (int r = 0; r < 4; r++) o[r] = f2bf(fmaxf(s[r] * G + B, 0.f));
    *(u16x4*)((unsigned short*)out + (size_t)n * Ostride + Ocoloff + c) = o;
  }
  if constexpr (MODE == RED_PVDIV) {
    float inv = 1.0f / rowsum[n];
    u16x4 o;
#pragma unroll
    for (int r = 0; r < 4; r++) o[r] = f2bf(s[r] * inv);
    *(u16x4*)((unsigned short*)out + (size_t)n * Ostride + Ocoloff + c) = o;
  }
  if constexpr (MODE == RED_BNR_F32) {
    float G = g1[n], B = b1[n];
    f32x4 o;
#pragma unroll
    for (int r = 0; r < 4; r++) o[r] = fmaxf(s[r] * G + B, 0.f);
    *(f32x4*)((float*)out + (size_t)n * Ostride + c) = o;
  }
}

// fp32 NCHW frame -> bf16 channel-last [pos][c]
__global__ __launch_bounds__(256) void nchw_to_cl(const float* __restrict__ src,
                                                  unsigned short* __restrict__ dst,
                                                  int C, int P) {
  __shared__ float t[32][33];
  int f = blockIdx.z;
  src += (size_t)f * C * P;
  dst += (size_t)f * C * P;
  int p0 = blockIdx.x * 32, c0 = blockIdx.y * 32;
  int a = threadIdx.x & 31, b = threadIdx.x >> 5;
#pragma unroll
  for (int k = 0; k < 4; k++)
    t[b + 8 * k][a] = src[(size_t)(c0 + b + 8 * k) * P + p0 + a];
  __syncthreads();
#pragma unroll
  for (int k = 0; k < 4; k++)
    dst[(size_t)(p0 + b + 8 * k) * C + c0 + a] = f2bf(t[a][b + 8 * k]);
}

__global__ __launch_bounds__(256) void cvt_bf16(const float* __restrict__ s,
                                                unsigned short* __restrict__ d, int n) {
  int i = blockIdx.x * 256 + threadIdx.x;
  if (i < n) d[i] = f2bf(s[i]);
}

// [co][ci][3][3] fp32 -> [co][kh][kw][ci] bf16
__global__ __launch_bounds__(256) void repack3(const float* __restrict__ s,
                                               unsigned short* __restrict__ d,
                                               int ci_log2, int n) {
  int i = blockIdx.x * 256 + threadIdx.x;
  if (i >= n) return;
  int Ci = 1 << ci_log2;
  int ci = i & (Ci - 1);
  int t = i >> ci_log2;
  int e = t % 9;
  int co = t / 9;
  d[i] = f2bf(s[((size_t)co * Ci + ci) * 9 + e]);
}

__global__ __launch_bounds__(256) void fillf(float* p, float v, int n) {
  int i = blockIdx.x * 256 + threadIdx.x;
  if (i < n) p[i] = v;
}

extern "C" void kernel_launch(void* const* d_in, const int* in_sizes, int n_in,
                              void* d_out, int out_size, void* d_ws, size_t ws_size,
                              hipStream_t stream) {
  (void)in_sizes; (void)n_in;
  const float* x    = (const float*)d_in[0];
  const float* seq  = (const float*)d_in[1];
  const float* wk1  = (const float*)d_in[2];
  const float* gk1  = (const float*)d_in[3];
  const float* bk1  = (const float*)d_in[4];
  const float* wk2  = (const float*)d_in[5];
  const float* gk2  = (const float*)d_in[6];
  const float* bk2  = (const float*)d_in[7];
  const float* wv1  = (const float*)d_in[8];
  const float* gv1  = (const float*)d_in[9];
  const float* bv1  = (const float*)d_in[10];
  const float* wv2  = (const float*)d_in[11];
  const float* gv2  = (const float*)d_in[12];
  const float* bv2  = (const float*)d_in[13];
  const float* wqk1 = (const float*)d_in[14];
  const float* gqk1 = (const float*)d_in[15];
  const float* bqk1 = (const float*)d_in[16];
  const float* wqk2 = (const float*)d_in[17];
  const float* gqk2 = (const float*)d_in[18];
  const float* bqk2 = (const float*)d_in[19];
  const float* wqv1 = (const float*)d_in[20];
  const float* gqv1 = (const float*)d_in[21];
  const float* bqv1 = (const float*)d_in[22];
  const float* wqv2 = (const float*)d_in[23];
  const float* gqv2 = (const float*)d_in[24];
  const float* bqv2 = (const float*)d_in[25];
  const float* wb   = (const float*)d_in[26];
  const float* gb   = (const float*)d_in[27];
  const float* bb   = (const float*)d_in[28];

  const size_t MB = 1024 * 1024;
  char* ws = (char*)d_ws;
  size_t off = 0;
  auto alloc = [&](size_t bytes) { size_t o = off; off += (bytes + 255) & ~(size_t)255; return o; };
  size_t o_zp    = alloc(4096);
  size_t o_rs    = alloc(4096 * 4);
  size_t o_wKV1  = alloc((size_t)768 * 1024 * 2);
  size_t o_wQKV1 = alloc((size_t)768 * 1024 * 2);
  size_t o_wK2   = alloc((size_t)256 * 2304 * 2);
  size_t o_wQK2  = alloc((size_t)256 * 2304 * 2);
  size_t o_wV2   = alloc((size_t)512 * 4608 * 2);
  size_t o_wQV2  = alloc((size_t)512 * 4608 * 2);
  size_t o_wB    = alloc((size_t)512 * 9216 * 2);
  size_t o_mk    = alloc((size_t)16384 * 256 * 2);
  size_t o_mv    = alloc((size_t)512 * 16384 * 2);
  size_t o_qk    = alloc((size_t)4096 * 256 * 2);
  size_t o_qvm   = alloc((size_t)4096 * 1024 * 2);
  size_t off_fixed = off;

  // volatile region sizes
  size_t sz_xT   = (size_t)4096 * 1024 * 2;
  size_t sz_seqT = (size_t)4 * 4096 * 1024 * 2;
  size_t sz_kv1  = (size_t)16384 * 768 * 2;
  size_t sz_qkv1 = (size_t)4096 * 768 * 2;
  size_t sz_vol1 = sz_xT + sz_seqT + sz_kv1 + sz_qkv1 + 4096;
  size_t sz_expS = (size_t)4096 * 16384 * 2;
  size_t sz_vol  = sz_vol1 > sz_expS ? sz_vol1 : sz_expS;

  // tier selection: 128MB partials -> doubled z; 64MB -> round-7 z; else direct
  size_t psize = 0;
  if (ws_size >= off_fixed + 128 * MB + sz_vol)      psize = 128 * MB;
  else if (ws_size >= off_fixed + 64 * MB + sz_vol)  psize = 64 * MB;

  size_t o_part = off_fixed;
  size_t o_vol  = off_fixed + psize;
  size_t o_xT   = o_vol;
  size_t o_seqT = o_xT + sz_xT;
  size_t o_kv1  = o_seqT + sz_seqT;
  size_t o_qkv1 = o_kv1 + sz_kv1;
  size_t o_expS = o_vol;

  bool SPLIT = psize != 0;
  if (!SPLIT && ws_size < off_fixed + sz_vol) {
    fillf<<<(out_size + 255) / 256, 256, 0, stream>>>((float*)d_out, 12345.0f, out_size);
    return;
  }

  // z config per tier
  int zmk, zqv, zmv, zpv, zfin;
  if (psize >= 128 * MB) { zmk = 8; zqv = 16; zmv = 4; zpv = 16; zfin = 16; }
  else                   { zmk = 4; zqv = 8;  zmv = 2; zpv = 8;  zfin = 8;  }

  const char* zp = ws + o_zp;
  float* rs = (float*)(ws + o_rs);
  unsigned short* wKV1p  = (unsigned short*)(ws + o_wKV1);
  unsigned short* wQKV1p = (unsigned short*)(ws + o_wQKV1);
  unsigned short* wK2p   = (unsigned short*)(ws + o_wK2);
  unsigned short* wQK2p  = (unsigned short*)(ws + o_wQK2);
  unsigned short* wV2p   = (unsigned short*)(ws + o_wV2);
  unsigned short* wQV2p  = (unsigned short*)(ws + o_wQV2);
  unsigned short* wBp    = (unsigned short*)(ws + o_wB);
  unsigned short* mkp    = (unsigned short*)(ws + o_mk);
  unsigned short* mvp    = (unsigned short*)(ws + o_mv);
  unsigned short* qkp    = (unsigned short*)(ws + o_qk);
  unsigned short* qvmp   = (unsigned short*)(ws + o_qvm);
  float* partp           = (float*)(ws + o_part);
  unsigned short* xTp    = (unsigned short*)(ws + o_xT);
  unsigned short* seqTp  = (unsigned short*)(ws + o_seqT);
  unsigned short* kv1p   = (unsigned short*)(ws + o_kv1);
  unsigned short* qkv1p  = (unsigned short*)(ws + o_qkv1);
  unsigned short* expSp  = (unsigned short*)(ws + o_expS);

  hipMemsetAsync(ws + o_zp, 0, 4096, stream);
  hipMemsetAsync(ws + o_rs, 0, 4096 * 4, stream);

  // --- weight prep ---
  cvt_bf16<<<(256 * 1024 + 255) / 256, 256, 0, stream>>>(wk1, wKV1p, 256 * 1024);
  cvt_bf16<<<(512 * 1024 + 255) / 256, 256, 0, stream>>>(wv1, wKV1p + 256 * 1024, 512 * 1024);
  cvt_bf16<<<(256 * 1024 + 255) / 256, 256, 0, stream>>>(wqk1, wQKV1p, 256 * 1024);
  cvt_bf16<<<(512 * 1024 + 255) / 256, 256, 0, stream>>>(wqv1, wQKV1p + 256 * 1024, 512 * 1024);
  repack3<<<(256 * 2304 + 255) / 256, 256, 0, stream>>>(wk2, wK2p, 8, 256 * 2304);
  repack3<<<(256 * 2304 + 255) / 256, 256, 0, stream>>>(wqk2, wQK2p, 8, 256 * 2304);
  repack3<<<(512 * 4608 + 255) / 256, 256, 0, stream>>>(wv2, wV2p, 9, 512 * 4608);
  repack3<<<(512 * 4608 + 255) / 256, 256, 0, stream>>>(wqv2, wQV2p, 9, 512 * 4608);
  repack3<<<(512 * 9216 + 255) / 256, 256, 0, stream>>>(wb, wBp, 10, 512 * 9216);

  // --- input layout: fp32 NCHW -> bf16 [pos][c] ---
  nchw_to_cl<<<dim3(128, 32, 1), 256, 0, stream>>>(x, xTp, 1024, 4096);
  nchw_to_cl<<<dim3(128, 32, 4), 256, 0, stream>>>(seq, seqTp, 1024, 4096);

  if (SPLIT) {
    // kv1 (gemm256, fused): m=co 768, n=pos 16384 -> grid (64,3) = 192 blocks
    gemm256<G_CL, false, false, false><<<dim3(64, 3), 512, 0, stream>>>(
        wKV1p, seqTp, 1024, 1024, 1024, 0, 0, kv1p, 768, 0,
        gk1, bk1, gv1, bv1, 256, rs, zp);
    // qkv1 (gemm_k direct fused): 192 blocks
    gemm_k<EP_CL_BNR, false, false, false><<<dim3(32, 6), 256, 0, stream>>>(
        wQKV1p, xTp, 1024, 1024, 1024, 0, 0, qkv1p, 768, 0, 0,
        gqk1, bqk1, gqv1, bqv1, 256, rs, zp);
    // mk (gemm256): m=co 256, n=pos 16384
    {
      size_t plane = (size_t)16384 * 256;
      gemm256<G_PART, false, true, false><<<dim3(64, 1, zmk), 512, 0, stream>>>(
          wK2p, kv1p, 2304, 2304 / zmk, 768, 0, 8, partp, 256, plane,
          nullptr, nullptr, nullptr, nullptr, 0, rs, zp);
      int t4 = (int)(plane / 4);
      reduce_k<RED_BNR_BF16><<<(t4 + 255) / 256, 256, 0, stream>>>(
          partp, zmk, plane, 256, mkp, 256, 0, gk2, bk2, gk2, bk2, 256, rs, t4);
    }
    // qk: z=8 -> 512 blocks (gemm_k)
    {
      size_t plane = (size_t)4096 * 256;
      gemm_k<EP_PART, false, true, false><<<dim3(32, 2, 8), 256, 0, stream>>>(
          wQK2p, qkv1p, 2304, 288, 768, 0, 8, partp, 256, 0, plane,
          nullptr, nullptr, nullptr, nullptr, 0, rs, zp);
      int t4 = (int)(plane / 4);
      reduce_k<RED_BNR_BF16><<<(t4 + 255) / 256, 256, 0, stream>>>(
          partp, 8, plane, 256, qkp, 256, 0, gqk2, bqk2, gqk2, bqk2, 256, rs, t4);
    }
    // qv (gemm256): m=co 512, n=pos 4096
    {
      size_t plane = (size_t)4096 * 512;
      gemm256<G_PART, false, true, false><<<dim3(16, 2, zqv), 512, 0, stream>>>(
          wQV2p, qkv1p, 4608, 4608 / zqv, 768, 256, 9, partp, 512, plane,
          nullptr, nullptr, nullptr, nullptr, 0, rs, zp);
      int t4 = (int)(plane / 4);
      reduce_k<RED_BNR_BF16><<<(t4 + 255) / 256, 256, 0, stream>>>(
          partp, zqv, plane, 512, qvmp, 1024, 0, gqv2, bqv2, gqv2, bqv2, 512, rs, t4);
    }
    // mv (gemm256, CF): m=pos 16384, n=co 512
    {
      size_t plane = (size_t)512 * 16384;
      gemm256<G_PART, true, true, false><<<dim3(2, 64, zmv), 512, 0, stream>>>(
          wV2p, kv1p, 4608, 4608 / zmv, 768, 256, 9, partp, 16384, plane,
          nullptr, nullptr, nullptr, nullptr, 0, rs, zp);
      int t4 = (int)(plane / 4);
      reduce_k<RED_BNR_BF16_N><<<(t4 + 255) / 256, 256, 0, stream>>>(
          partp, zmv, plane, 16384, mvp, 16384, 0, gv2, bv2, nullptr, nullptr, 0, rs, t4);
    }
    // S-pass (gemm256 EXPSUM): m=kpos 16384, n=q 4096 -> 1024 blocks
    gemm256<G_EXPSUM, false, false, false><<<dim3(16, 64), 512, 0, stream>>>(
        mkp, qkp, 256, 256, 256, 0, 0, expSp, 4096, 0,
        nullptr, nullptr, nullptr, nullptr, 0, rs, zp);
    // PV (gemm256, XTILED): m=c 512, n=q 4096
    {
      size_t plane = (size_t)4096 * 512;
      gemm256<G_PART, false, false, true><<<dim3(16, 2, zpv), 512, 0, stream>>>(
          mvp, expSp, 16384, 16384 / zpv, 4096, 0, 0, partp, 512, plane,
          nullptr, nullptr, nullptr, nullptr, 0, rs, zp);
      int t4 = (int)(plane / 4);
      reduce_k<RED_PVDIV><<<(t4 + 255) / 256, 256, 0, stream>>>(
          partp, zpv, plane, 512, qvmp, 1024, 512, nullptr, nullptr, nullptr, nullptr, 0, rs, t4);
    }
    // final conv3x3 (gemm256, CF): m=pos 4096, n=co 512
    {
      size_t plane = (size_t)512 * 4096;
      gemm256<G_PART, true, true, false><<<dim3(2, 16, zfin), 512, 0, stream>>>(
          wBp, qvmp, 9216, 9216 / zfin, 1024, 0, 10, partp, 4096, plane,
          nullptr, nullptr, nullptr, nullptr, 0, rs, zp);
      int t4 = (int)(plane / 4);
      reduce_k<RED_BNR_F32><<<(t4 + 255) / 256, 256, 0, stream>>>(
          partp, zfin, plane, 4096, (float*)d_out, 4096, 0, gb, bb, gb, bb, 512, rs, t4);
    }
  } else {
    // fallback: direct kernels, row-major expS
    gemm_k<EP_CL_BNR, false, false, false><<<dim3(128, 6), 256, 0, stream>>>(
        wKV1p, seqTp, 1024, 1024, 1024, 0, 0, kv1p, 768, 0, 0,
        gk1, bk1, gv1, bv1, 256, rs, zp);
    gemm_k<EP_CL_BNR, false, false, false><<<dim3(32, 6), 256, 0, stream>>>(
        wQKV1p, xTp, 1024, 1024, 1024, 0, 0, qkv1p, 768, 0, 0,
        gqk1, bqk1, gqv1, bqv1, 256, rs, zp);
    gemm_k<EP_CL_BNR, false, true, false><<<dim3(128, 2), 256, 0, stream>>>(
        wK2p, kv1p, 2304, 2304, 768, 0, 8, mkp, 256, 0, 0,
        gk2, bk2, gk2, bk2, 256, rs, zp);
    gemm_k<EP_CL_BNR, false, true, false><<<dim3(32, 2), 256, 0, stream>>>(
        wQK2p, qkv1p, 2304, 2304, 768, 0, 8, qkp, 256, 0, 0,
        gqk2, bqk2, gqk2, bqk2, 256, rs, zp);
    gemm_k<EP_CL_BNR, false, true, false><<<dim3(32, 4), 256, 0, stream>>>(
        wQV2p, qkv1p, 4608, 4608, 768, 256, 9, qvmp, 1024, 0, 0,
        gqv2, bqv2, gqv2, bqv2, 512, rs, zp);
    gemm_k<EP_CF_BNR_BF16, true, true, false><<<dim3(4, 128), 256, 0, stream>>>(
        wV2p, kv1p, 4608, 4608, 768, 256, 9, mvp, 16384, 0, 0,
        gv2, bv2, gv2, bv2, 512, rs, zp);
    gemm_k<EP_EXPSUM, false, false, false><<<dim3(32, 128), 256, 0, stream>>>(
        mkp, qkp, 256, 256, 256, 0, 0, expSp, 16384, 0, 0,
        nullptr, nullptr, nullptr, nullptr, 0, rs, zp);
    gemm_k<EP_PVDIV, false, false, false><<<dim3(32, 4), 256, 0, stream>>>(
        mvp, expSp, 16384, 16384, 16384, 0, 0, qvmp, 1024, 512, 0,
        nullptr, nullptr, nullptr, nullptr, 0, rs, zp);
    gemm_k<EP_CF_BNR_F32, true, true, false><<<dim3(4, 32), 256, 0, stream>>>(
        wBp, qvmp, 9216, 9216, 1024, 0, 10, (float*)d_out, 4096, 0, 0,
        gb, bb, gb, bb, 512, rs, zp);
  }
}

// Round 12
// 632.857 us; speedup vs baseline: 5.4001x; 5.4001x over previous
//
#include <hip/hip_runtime.h>
#include <stdint.h>

// ---------------------------------------------------------------------------
// TMA head on MI355X. Round 12: fixes round-9/11's pipeline RACE in gemm256's
// BK=32 loop. Correct order (proven in gemm_k): stage(next) -> vmcnt(4) ->
// barrier -> ds_read(cur) -> MFMA -> barrier. The vmcnt drains each wave's
// writes to the buffer being published; 4 newest loads stay in flight.
// launch_bounds(512,2) (no spill), fp32 partials, tiered 128MB doubled-z.
// ---------------------------------------------------------------------------

typedef short bf16x8 __attribute__((ext_vector_type(8)));
typedef float f32x4  __attribute__((ext_vector_type(4)));
typedef unsigned short u16x4 __attribute__((ext_vector_type(4)));

__device__ __forceinline__ unsigned short f2bf(float f) {
  union { float f; unsigned u; } x; x.f = f;
  unsigned r = x.u + 0x7FFFu + ((x.u >> 16) & 1u);   // RNE
  return (unsigned short)(r >> 16);
}

typedef const __attribute__((address_space(1))) char* as1cp;
typedef __attribute__((address_space(3))) char* as3p;

__device__ __forceinline__ void gl_lds16(const char* g, char* l) {
  __builtin_amdgcn_global_load_lds((as1cp)g, (as3p)l, 16, 0, 0);
}

enum { G_PART = 0, G_CL = 1, G_EXPSUM = 2 };

// ===========================================================================
// gemm256: 256x256 tile, BK=32, 512 threads (8 waves: 2 m-rows x 4 n-cols),
// 64KB LDS -> 2 blocks/CU. Loop: {stage next (4 gl_lds), vmcnt(4), barrier,
// 12 ds_read, 32 MFMA (setprio), barrier}. Counted wait never drains in
// steady state AND guarantees the published buffer is complete.
// Swizzled LDS panels (0 bank conflicts); XCD block swizzle.
// EP: G_PART  -> fp32 partials P[z][gn][gm]
//     G_CL    -> bf16 out[gn(pos)][gm(co)] with BN(gsplit)+ReLU fused
//     G_EXPSUM-> exp() to tiled expS [gm/32][Ostride=qtot][gm&31] + rowsum
// ===========================================================================
template<int EP, bool CF, bool CONV3, bool XTILED>
__global__ __launch_bounds__(512, 2) void gemm256(
    const unsigned short* __restrict__ Wp,   // [rows][K] bf16
    const unsigned short* __restrict__ Xp,   // activations (or tiled expS)
    int K, int Kc, int Xstride, int Xcoloff, int cin_log2,
    void* __restrict__ Op, int Ostride, size_t plane,
    const float* __restrict__ g1, const float* __restrict__ b1,
    const float* __restrict__ g2, const float* __restrict__ b2, int gsplit,
    float* __restrict__ rowsum, const char* __restrict__ zp)
{
  __shared__ short Ap[2][8192];   // [buf][1024 slots * 8 shorts] = 16KB each
  __shared__ short Bp[2][8192];
  const int tid = threadIdx.x;
  const int w = tid >> 6;
  const int l = tid & 63;
  const int wm_idx = w >> 2;     // 0..1
  const int wn_idx = w & 3;      // 0..3

  // XCD-aware bijective block swizzle (nwg % 8 == 0 for all call sites)
  int bx = blockIdx.x, by = blockIdx.y;
  {
    int nwg = gridDim.x * gridDim.y;
    if ((nwg & 7) == 0) {
      int id = bx + gridDim.x * by;
      id = (id & 7) * (nwg >> 3) + (id >> 3);
      bx = id % gridDim.x;
      by = id / gridDim.x;
    }
  }
  const int n0 = bx * 256;
  const int m0 = by * 256;
  const int wrow0 = CF ? n0 : m0;
  const int xrow0 = CF ? m0 : n0;

  // staging lane constants: g = (l&7)^(l>>3), rows grow0/grow0+16
  const int g = (l & 7) ^ (l >> 3);
  const int grow0 = w * 32 + 2 * (l >> 3) + (g >> 2);
  const int gc = g & 3;

  auto srcW = [&](int grow, int k0) -> const char* {
    return (const char*)Wp +
           (((size_t)(wrow0 + grow)) * K + (size_t)(k0 + gc * 8)) * 2;
  };
  auto srcX = [&](int grow, int k0) -> const char* {
    if constexpr (XTILED) {
      return (const char*)Xp + (size_t)(k0 >> 5) * ((size_t)Xstride * 64)
             + (size_t)(xrow0 + grow) * 64 + gc * 16;
    } else if constexpr (CONV3) {
      int e = k0 >> cin_log2;
      int ci0 = k0 & ((1 << cin_log2) - 1);
      int kh = e / 3, kw = e - kh * 3;
      int dpos = (kh - 1) * 64 + (kw - 1);
      int p = xrow0 + grow;
      int hw = p & 4095;
      int h2 = (hw >> 6) + kh - 1, w2 = (hw & 63) + kw - 1;
      return ((unsigned)h2 < 64u && (unsigned)w2 < 64u)
          ? (const char*)Xp + (((size_t)(p + dpos)) * Xstride
                               + (size_t)(Xcoloff + ci0 + gc * 8)) * 2
          : zp + gc * 16;
    } else {
      return (const char*)Xp + (((size_t)(xrow0 + grow)) * Xstride
                                + (size_t)(Xcoloff + k0 + gc * 8)) * 2;
    }
  };

  // stage 32-k panels of tile at k0 into buffer b: 4 gl_lds per thread
  auto stage = [&](int b, int k0) {
#pragma unroll
    for (int j = 0; j < 2; j++) {
      int grow = grow0 + j * 16;
      const char* sm = CF ? srcX(grow, k0) : srcW(grow, k0);
      gl_lds16(sm, (char*)&Ap[b][0] + w * 2048 + j * 1024);
    }
#pragma unroll
    for (int j = 0; j < 2; j++) {
      int grow = grow0 + j * 16;
      const char* sn = CF ? srcW(grow, k0) : srcX(grow, k0);
      gl_lds16(sn, (char*)&Bp[b][0] + w * 2048 + j * 1024);
    }
  };

  auto rd = [&](const short* base, int row, int ks) -> bf16x8 {
    int R = row >> 1;
    int sp = (((row & 1) << 2) | ks) ^ (R & 7);
    return *(const bf16x8*)(base + R * 64 + sp * 8);
  };

  f32x4 acc[8][4] = {};

  const int kb = blockIdx.z * Kc;
  const int NT = Kc >> 5;

  stage(0, kb);
  int buf = 0;
  for (int t = 0; t < NT; ++t) {
    // stage NEXT tile first, then drain THIS tile's loads (leaves 4 in flight)
    if (t + 1 < NT) {
      stage(buf ^ 1, kb + (t + 1) * 32);
      asm volatile("s_waitcnt vmcnt(4)" ::: "memory");
    } else {
      asm volatile("s_waitcnt vmcnt(0)" ::: "memory");
    }
    __builtin_amdgcn_s_barrier();

    const short* Am = &Ap[buf][0];
    const short* Bm = &Bp[buf][0];
    bf16x8 af[8], bfv[4];
#pragma unroll
    for (int i = 0; i < 8; i++)
      af[i] = rd(Am, wm_idx * 128 + i * 16 + (l & 15), l >> 4);
#pragma unroll
    for (int j = 0; j < 4; j++)
      bfv[j] = rd(Bm, wn_idx * 64 + j * 16 + (l & 15), l >> 4);
    __builtin_amdgcn_s_setprio(1);
#pragma unroll
    for (int i = 0; i < 8; i++)
#pragma unroll
      for (int j = 0; j < 4; j++)
        acc[i][j] = __builtin_amdgcn_mfma_f32_16x16x32_bf16(af[i], bfv[j], acc[i][j], 0, 0, 0);
    __builtin_amdgcn_s_setprio(0);
    __builtin_amdgcn_s_barrier();
    buf ^= 1;
  }

  const int col = l & 15;
  const int rb2 = (l >> 4) << 2;

  if constexpr (EP == G_PART) {
    float* Pz = (float*)Op + (size_t)blockIdx.z * plane;
#pragma unroll
    for (int j = 0; j < 4; j++) {
      int gn = n0 + wn_idx * 64 + j * 16 + col;
#pragma unroll
      for (int i = 0; i < 8; i++) {
        int gm = m0 + wm_idx * 128 + i * 16 + rb2;
        *(f32x4*)(Pz + (size_t)gn * Ostride + gm) = acc[i][j];
      }
    }
  }
  if constexpr (EP == G_CL) {
    // out[gn(pos)][gm(co)] bf16, BN(gsplit on gm)+ReLU
#pragma unroll
    for (int i = 0; i < 8; i++) {
      int gm = m0 + wm_idx * 128 + i * 16 + rb2;
      const float* gp; const float* bp;
      if (gm < gsplit) { gp = g1 + gm; bp = b1 + gm; }
      else             { gp = g2 + (gm - gsplit); bp = b2 + (gm - gsplit); }
      float G[4], B[4];
#pragma unroll
      for (int r = 0; r < 4; r++) { G[r] = gp[r]; B[r] = bp[r]; }
#pragma unroll
      for (int j = 0; j < 4; j++) {
        int gn = n0 + wn_idx * 64 + j * 16 + col;
        f32x4 v = acc[i][j];
        u16x4 o;
#pragma unroll
        for (int r = 0; r < 4; r++) o[r] = f2bf(fmaxf(v[r] * G[r] + B[r], 0.f));
        *(u16x4*)((unsigned short*)Op + (size_t)gn * Ostride + gm) = o;
      }
    }
  }
  if constexpr (EP == G_EXPSUM) {
    // gm = kpos, gn = q; tiled expS [kpos/32][Ostride=qtot][kpos&31] + rowsum
#pragma unroll
    for (int j = 0; j < 4; j++) {
      int gn = n0 + wn_idx * 64 + j * 16 + col;   // q
      float s = 0.f;
#pragma unroll
      for (int i = 0; i < 8; i++) {
        int gm = m0 + wm_idx * 128 + i * 16 + rb2;  // kpos
        f32x4 v = acc[i][j];
        u16x4 o;
#pragma unroll
        for (int r = 0; r < 4; r++) { float e = __expf(v[r]); s += e; o[r] = f2bf(e); }
        *(u16x4*)((unsigned short*)Op + (size_t)(gm >> 5) * ((size_t)Ostride * 32)
                  + (size_t)gn * 32 + (gm & 31)) = o;
      }
      s += __shfl_xor(s, 16);
      s += __shfl_xor(s, 32);
      if (l < 16) atomicAdd(rowsum + gn, s);
    }
  }
}

enum { EP_CL_BNR = 0, EP_CF_BNR_BF16 = 1, EP_CF_BNR_F32 = 2, EP_EXPSUM = 3,
       EP_PVDIV = 4, EP_PART = 5 };

// 128x128 tile, BK=32, 256 threads (4 waves). Depth-2 pipeline. fp32 partials.
template<int EP, bool CF, bool CONV3, bool XTILED>
__global__ __launch_bounds__(256) void gemm_k(
    const unsigned short* __restrict__ Wp,
    const unsigned short* __restrict__ Xp,
    int K, int Kc, int Xstride, int Xcoloff, int cin_log2,
    void* __restrict__ Op, int Ostride, int Ocoloff, size_t plane,
    const float* __restrict__ g1, const float* __restrict__ b1,
    const float* __restrict__ g2, const float* __restrict__ b2, int gsplit,
    float* __restrict__ rowsum, const char* __restrict__ zp)
{
  __shared__ short Wt[2][128 * 32];
  __shared__ short Xt[2][128 * 32];
  const int tid = threadIdx.x;
  const int w = tid >> 6;
  const int l = tid & 63;
  const int m0 = blockIdx.y * 128;
  const int n0 = blockIdx.x * 128;
  const int wrow0 = CF ? n0 : m0;
  const int xrow0 = CF ? m0 : n0;

  const int ch0 = w, ch1 = w + 4;
  const int sr0 = ch0 * 16 + (l >> 2);
  const int sr1 = ch1 * 16 + (l >> 2);
  const int kbp = (l & 3) << 4;
  const int kbl0 = kbp ^ ((sr0 & 3) << 4);
  const int kbl1 = kbp ^ ((sr1 & 3) << 4);

  const size_t wrb = (size_t)K * 2;
  const size_t xrb = (size_t)Xstride * 2;

  const int wm = (w >> 1) * 64;
  const int wn = (w & 1) * 64;

  const int k_begin = blockIdx.z * Kc;
  const int k_end = (k_begin + Kc < K) ? (k_begin + Kc) : K;

  auto stage = [&](int b, int k0) {
    int ci0 = k0, kh = 1, kw = 1, dpos = 0;
    if (CONV3) {
      int e = k0 >> cin_log2;
      ci0 = k0 & ((1 << cin_log2) - 1);
      kh = e / 3; kw = e - kh * 3;
      dpos = (kh - 1) * 64 + (kw - 1);
    }
    char* Wl = (char*)&Wt[b][0];
    char* Xl = (char*)&Xt[b][0];
    gl_lds16((const char*)Wp + (size_t)(wrow0 + sr0) * wrb + (size_t)k0 * 2 + kbl0,
             Wl + ch0 * 1024);
    gl_lds16((const char*)Wp + (size_t)(wrow0 + sr1) * wrb + (size_t)k0 * 2 + kbl1,
             Wl + ch1 * 1024);
    const char* xs0;
    const char* xs1;
    if constexpr (XTILED) {
      size_t kslab = (size_t)(k0 >> 5) * ((size_t)Xstride * 64);
      xs0 = (const char*)Xp + kslab + (size_t)(xrow0 + sr0) * 64 + kbl0;
      xs1 = (const char*)Xp + kslab + (size_t)(xrow0 + sr1) * 64 + kbl1;
    } else if constexpr (CONV3) {
      int p = xrow0 + sr0;
      int hw = p & 4095;
      int h2 = (hw >> 6) + kh - 1, w2 = (hw & 63) + kw - 1;
      xs0 = ((unsigned)h2 < 64u && (unsigned)w2 < 64u)
          ? (const char*)Xp + (size_t)(p + dpos) * xrb + (size_t)(Xcoloff + ci0) * 2 + kbl0
          : zp + kbl0;
      p = xrow0 + sr1;
      hw = p & 4095;
      h2 = (hw >> 6) + kh - 1; w2 = (hw & 63) + kw - 1;
      xs1 = ((unsigned)h2 < 64u && (unsigned)w2 < 64u)
          ? (const char*)Xp + (size_t)(p + dpos) * xrb + (size_t)(Xcoloff + ci0) * 2 + kbl1
          : zp + kbl1;
    } else {
      xs0 = (const char*)Xp + (size_t)(xrow0 + sr0) * xrb + (size_t)(Xcoloff + k0) * 2 + kbl0;
      xs1 = (const char*)Xp + (size_t)(xrow0 + sr1) * xrb + (size_t)(Xcoloff + k0) * 2 + kbl1;
    }
    gl_lds16(xs0, Xl + ch0 * 1024);
    gl_lds16(xs1, Xl + ch1 * 1024);
  };

  f32x4 acc[4][4] = {};

  int cur = 0;
  stage(0, k_begin);
  for (int k0 = k_begin; k0 < k_end; k0 += 32) {
    if (k0 + 32 < k_end) {
      stage(cur ^ 1, k0 + 32);
      asm volatile("s_waitcnt vmcnt(4)" ::: "memory");
    } else {
      asm volatile("s_waitcnt vmcnt(0)" ::: "memory");
    }
    __builtin_amdgcn_s_barrier();

    const short* Wb = &Wt[cur][0];
    const short* Xb = &Xt[cur][0];
    const short* At = CF ? Xb : Wb;
    const short* Bt = CF ? Wb : Xb;

    bf16x8 af[4], bfv[4];
#pragma unroll
    for (int i = 0; i < 4; i++) {
      int row = wm + i * 16 + (l & 15);
      int kb = ((l >> 4) << 4) ^ ((row & 3) << 4);
      af[i] = *(const bf16x8*)(At + row * 32 + (kb >> 1));
    }
#pragma unroll
    for (int j = 0; j < 4; j++) {
      int row = wn + j * 16 + (l & 15);
      int kb = ((l >> 4) << 4) ^ ((row & 3) << 4);
      bfv[j] = *(const bf16x8*)(Bt + row * 32 + (kb >> 1));
    }
#pragma unroll
    for (int i = 0; i < 4; i++)
#pragma unroll
      for (int j = 0; j < 4; j++)
        acc[i][j] = __builtin_amdgcn_mfma_f32_16x16x32_bf16(af[i], bfv[j], acc[i][j], 0, 0, 0);

    __builtin_amdgcn_s_barrier();
    cur ^= 1;
  }

  const int col = l & 15;
  const int rb = (l >> 4) << 2;

  if constexpr (EP == EP_PART) {
    float* P = (float*)Op + (size_t)blockIdx.z * plane;
#pragma unroll
    for (int j = 0; j < 4; j++) {
      int gn = n0 + wn + j * 16 + col;
#pragma unroll
      for (int i = 0; i < 4; i++) {
        int gm = m0 + wm + i * 16 + rb;
        *(f32x4*)(P + (size_t)gn * Ostride + gm) = acc[i][j];
      }
    }
  }
  if constexpr (EP == EP_CL_BNR) {
#pragma unroll
    for (int i = 0; i < 4; i++) {
      int gm = m0 + wm + i * 16 + rb;
      const float* gp; const float* bp;
      if (gm < gsplit) { gp = g1 + gm; bp = b1 + gm; }
      else             { gp = g2 + (gm - gsplit); bp = b2 + (gm - gsplit); }
      float G[4], B[4];
#pragma unroll
      for (int r = 0; r < 4; r++) { G[r] = gp[r]; B[r] = bp[r]; }
#pragma unroll
      for (int j = 0; j < 4; j++) {
        int gn = n0 + wn + j * 16 + col;
        f32x4 v = acc[i][j];
        u16x4 o;
#pragma unroll
        for (int r = 0; r < 4; r++) o[r] = f2bf(fmaxf(v[r] * G[r] + B[r], 0.f));
        *(u16x4*)((unsigned short*)Op + (size_t)gn * Ostride + Ocoloff + gm) = o;
      }
    }
  }
  if constexpr (EP == EP_CF_BNR_BF16 || EP == EP_CF_BNR_F32) {
#pragma unroll
    for (int j = 0; j < 4; j++) {
      int gn = n0 + wn + j * 16 + col;
      float G = (gn < gsplit) ? g1[gn] : g2[gn - gsplit];
      float Bv = (gn < gsplit) ? b1[gn] : b2[gn - gsplit];
#pragma unroll
      for (int i = 0; i < 4; i++) {
        int gm = m0 + wm + i * 16 + rb;
        f32x4 v = acc[i][j];
        if constexpr (EP == EP_CF_BNR_F32) {
          f32x4 o;
#pragma unroll
          for (int r = 0; r < 4; r++) o[r] = fmaxf(v[r] * G + Bv, 0.f);
          *(f32x4*)((float*)Op + (size_t)gn * Ostride + Ocoloff + gm) = o;
        } else {
          u16x4 o;
#pragma unroll
          for (int r = 0; r < 4; r++) o[r] = f2bf(fmaxf(v[r] * G + Bv, 0.f));
          *(u16x4*)((unsigned short*)Op + (size_t)gn * Ostride + Ocoloff + gm) = o;
        }
      }
    }
  }
  if constexpr (EP == EP_EXPSUM) {
#pragma unroll
    for (int j = 0; j < 4; j++) {
      int gn = n0 + wn + j * 16 + col;   // q
      float s = 0.f;
#pragma unroll
      for (int i = 0; i < 4; i++) {
        int gm = m0 + wm + i * 16 + rb;  // kpos
        f32x4 v = acc[i][j];
        u16x4 o;
#pragma unroll
        for (int r = 0; r < 4; r++) { float e = __expf(v[r]); s += e; o[r] = f2bf(e); }
        if (gsplit)
          *(u16x4*)((unsigned short*)Op + (size_t)(gm >> 5) * ((size_t)Ostride * 32)
                    + (size_t)gn * 32 + (gm & 31)) = o;
        else
          *(u16x4*)((unsigned short*)Op + (size_t)gn * Ostride + gm) = o;
      }
      s += __shfl_xor(s, 16);
      s += __shfl_xor(s, 32);
      if (l < 16) atomicAdd(rowsum + gn, s);
    }
  }
  if constexpr (EP == EP_PVDIV) {
#pragma unroll
    for (int j = 0; j < 4; j++) {
      int gn = n0 + wn + j * 16 + col;   // q
      float inv = 1.0f / rowsum[gn];
#pragma unroll
      for (int i = 0; i < 4; i++) {
        int gm = m0 + wm + i * 16 + rb;  // c
        f32x4 v = acc[i][j];
        u16x4 o;
#pragma unroll
        for (int r = 0; r < 4; r++) o[r] = f2bf(v[r] * inv);
        *(u16x4*)((unsigned short*)Op + (size_t)gn * Ostride + Ocoloff + gm) = o;
      }
    }
  }
}

// ---- split-K reduce: sum Z fp32 planes, apply epilogue ----
enum { RED_BNR_BF16 = 0, RED_PVDIV = 1, RED_BNR_F32 = 2, RED_BNR_BF16_N = 3 };

template<int MODE>
__global__ __launch_bounds__(256) void reduce_k(
    const float* __restrict__ P, int Z, size_t plane, int Cdim,
    void* __restrict__ out, int Ostride, int Ocoloff,
    const float* __restrict__ g1, const float* __restrict__ b1,
    const float* __restrict__ g2, const float* __restrict__ b2, int gsplit,
    const float* __restrict__ rowsum, int total4)
{
  int t = blockIdx.x * 256 + threadIdx.x;
  if (t >= total4) return;
  size_t base = (size_t)t * 4;
  int n = (int)(base / (size_t)Cdim);
  int c = (int)(base % (size_t)Cdim);
  f32x4 s = *(const f32x4*)(P + base);
  for (int z = 1; z < Z; z++) {
    f32x4 v = *(const f32x4*)(P + (size_t)z * plane + base);
    s += v;
  }
  if constexpr (MODE == RED_BNR_BF16) {
    u16x4 o;
#pragma unroll
    for (int r = 0; r < 4; r++) {
      int ch = c + r;
      float G = (ch < gsplit) ? g1[ch] : g2[ch - gsplit];
      float B = (ch < gsplit) ? b1[ch] : b2[ch - gsplit];
      o[r] = f2bf(fmaxf(s[r] * G + B, 0.f));
    }
    *(u16x4*)((unsigned short*)out + (size_t)n * Ostride + Ocoloff + c) = o;
  }
  if constexpr (MODE == RED_BNR_BF16_N) {
    float G = g1[n], B = b1[n];
    u16x4 o;
#pragma unroll
    for (int r = 0; r < 4; r++) o[r] = f2bf(fmaxf(s[r] * G + B, 0.f));
    *(u16x4*)((unsigned short*)out + (size_t)n * Ostride + Ocoloff + c) = o;
  }
  if constexpr (MODE == RED_PVDIV) {
    float inv = 1.0f / rowsum[n];
    u16x4 o;
#pragma unroll
    for (int r = 0; r < 4; r++) o[r] = f2bf(s[r] * inv);
    *(u16x4*)((unsigned short*)out + (size_t)n * Ostride + Ocoloff + c) = o;
  }
  if constexpr (MODE == RED_BNR_F32) {
    float G = g1[n], B = b1[n];
    f32x4 o;
#pragma unroll
    for (int r = 0; r < 4; r++) o[r] = fmaxf(s[r] * G + B, 0.f);
    *(f32x4*)((float*)out + (size_t)n * Ostride + c) = o;
  }
}

// fp32 NCHW frame -> bf16 channel-last [pos][c]
__global__ __launch_bounds__(256) void nchw_to_cl(const float* __restrict__ src,
                                                  unsigned short* __restrict__ dst,
                                                  int C, int P) {
  __shared__ float t[32][33];
  int f = blockIdx.z;
  src += (size_t)f * C * P;
  dst += (size_t)f * C * P;
  int p0 = blockIdx.x * 32, c0 = blockIdx.y * 32;
  int a = threadIdx.x & 31, b = threadIdx.x >> 5;
#pragma unroll
  for (int k = 0; k < 4; k++)
    t[b + 8 * k][a] = src[(size_t)(c0 + b + 8 * k) * P + p0 + a];
  __syncthreads();
#pragma unroll
  for (int k = 0; k < 4; k++)
    dst[(size_t)(p0 + b + 8 * k) * C + c0 + a] = f2bf(t[a][b + 8 * k]);
}

__global__ __launch_bounds__(256) void cvt_bf16(const float* __restrict__ s,
                                                unsigned short* __restrict__ d, int n) {
  int i = blockIdx.x * 256 + threadIdx.x;
  if (i < n) d[i] = f2bf(s[i]);
}

// [co][ci][3][3] fp32 -> [co][kh][kw][ci] bf16
__global__ __launch_bounds__(256) void repack3(const float* __restrict__ s,
                                               unsigned short* __restrict__ d,
                                               int ci_log2, int n) {
  int i = blockIdx.x * 256 + threadIdx.x;
  if (i >= n) return;
  int Ci = 1 << ci_log2;
  int ci = i & (Ci - 1);
  int t = i >> ci_log2;
  int e = t % 9;
  int co = t / 9;
  d[i] = f2bf(s[((size_t)co * Ci + ci) * 9 + e]);
}

__global__ __launch_bounds__(256) void fillf(float* p, float v, int n) {
  int i = blockIdx.x * 256 + threadIdx.x;
  if (i < n) p[i] = v;
}

extern "C" void kernel_launch(void* const* d_in, const int* in_sizes, int n_in,
                              void* d_out, int out_size, void* d_ws, size_t ws_size,
                              hipStream_t stream) {
  (void)in_sizes; (void)n_in;
  const float* x    = (const float*)d_in[0];
  const float* seq  = (const float*)d_in[1];
  const float* wk1  = (const float*)d_in[2];
  const float* gk1  = (const float*)d_in[3];
  const float* bk1  = (const float*)d_in[4];
  const float* wk2  = (const float*)d_in[5];
  const float* gk2  = (const float*)d_in[6];
  const float* bk2  = (const float*)d_in[7];
  const float* wv1  = (const float*)d_in[8];
  const float* gv1  = (const float*)d_in[9];
  const float* bv1  = (const float*)d_in[10];
  const float* wv2  = (const float*)d_in[11];
  const float* gv2  = (const float*)d_in[12];
  const float* bv2  = (const float*)d_in[13];
  const float* wqk1 = (const float*)d_in[14];
  const float* gqk1 = (const float*)d_in[15];
  const float* bqk1 = (const float*)d_in[16];
  const float* wqk2 = (const float*)d_in[17];
  const float* gqk2 = (const float*)d_in[18];
  const float* bqk2 = (const float*)d_in[19];
  const float* wqv1 = (const float*)d_in[20];
  const float* gqv1 = (const float*)d_in[21];
  const float* bqv1 = (const float*)d_in[22];
  const float* wqv2 = (const float*)d_in[23];
  const float* gqv2 = (const float*)d_in[24];
  const float* bqv2 = (const float*)d_in[25];
  const float* wb   = (const float*)d_in[26];
  const float* gb   = (const float*)d_in[27];
  const float* bb   = (const float*)d_in[28];

  const size_t MB = 1024 * 1024;
  char* ws = (char*)d_ws;
  size_t off = 0;
  auto alloc = [&](size_t bytes) { size_t o = off; off += (bytes + 255) & ~(size_t)255; return o; };
  size_t o_zp    = alloc(4096);
  size_t o_rs    = alloc(4096 * 4);
  size_t o_wKV1  = alloc((size_t)768 * 1024 * 2);
  size_t o_wQKV1 = alloc((size_t)768 * 1024 * 2);
  size_t o_wK2   = alloc((size_t)256 * 2304 * 2);
  size_t o_wQK2  = alloc((size_t)256 * 2304 * 2);
  size_t o_wV2   = alloc((size_t)512 * 4608 * 2);
  size_t o_wQV2  = alloc((size_t)512 * 4608 * 2);
  size_t o_wB    = alloc((size_t)512 * 9216 * 2);
  size_t o_mk    = alloc((size_t)16384 * 256 * 2);
  size_t o_mv    = alloc((size_t)512 * 16384 * 2);
  size_t o_qk    = alloc((size_t)4096 * 256 * 2);
  size_t o_qvm   = alloc((size_t)4096 * 1024 * 2);
  size_t off_fixed = off;

  // volatile region sizes
  size_t sz_xT   = (size_t)4096 * 1024 * 2;
  size_t sz_seqT = (size_t)4 * 4096 * 1024 * 2;
  size_t sz_kv1  = (size_t)16384 * 768 * 2;
  size_t sz_qkv1 = (size_t)4096 * 768 * 2;
  size_t sz_vol1 = sz_xT + sz_seqT + sz_kv1 + sz_qkv1 + 4096;
  size_t sz_expS = (size_t)4096 * 16384 * 2;
  size_t sz_vol  = sz_vol1 > sz_expS ? sz_vol1 : sz_expS;

  // tier selection: 128MB partials -> doubled z; 64MB -> round-7 z; else direct
  size_t psize = 0;
  if (ws_size >= off_fixed + 128 * MB + sz_vol)      psize = 128 * MB;
  else if (ws_size >= off_fixed + 64 * MB + sz_vol)  psize = 64 * MB;

  size_t o_part = off_fixed;
  size_t o_vol  = off_fixed + psize;
  size_t o_xT   = o_vol;
  size_t o_seqT = o_xT + sz_xT;
  size_t o_kv1  = o_seqT + sz_seqT;
  size_t o_qkv1 = o_kv1 + sz_kv1;
  size_t o_expS = o_vol;

  bool SPLIT = psize != 0;
  if (!SPLIT && ws_size < off_fixed + sz_vol) {
    fillf<<<(out_size + 255) / 256, 256, 0, stream>>>((float*)d_out, 12345.0f, out_size);
    return;
  }

  // z config per tier
  int zmk, zqv, zmv, zpv, zfin;
  if (psize >= 128 * MB) { zmk = 8; zqv = 16; zmv = 4; zpv = 16; zfin = 16; }
  else                   { zmk = 4; zqv = 8;  zmv = 2; zpv = 8;  zfin = 8;  }

  const char* zp = ws + o_zp;
  float* rs = (float*)(ws + o_rs);
  unsigned short* wKV1p  = (unsigned short*)(ws + o_wKV1);
  unsigned short* wQKV1p = (unsigned short*)(ws + o_wQKV1);
  unsigned short* wK2p   = (unsigned short*)(ws + o_wK2);
  unsigned short* wQK2p  = (unsigned short*)(ws + o_wQK2);
  unsigned short* wV2p   = (unsigned short*)(ws + o_wV2);
  unsigned short* wQV2p  = (unsigned short*)(ws + o_wQV2);
  unsigned short* wBp    = (unsigned short*)(ws + o_wB);
  unsigned short* mkp    = (unsigned short*)(ws + o_mk);
  unsigned short* mvp    = (unsigned short*)(ws + o_mv);
  unsigned short* qkp    = (unsigned short*)(ws + o_qk);
  unsigned short* qvmp   = (unsigned short*)(ws + o_qvm);
  float* partp           = (float*)(ws + o_part);
  unsigned short* xTp    = (unsigned short*)(ws + o_xT);
  unsigned short* seqTp  = (unsigned short*)(ws + o_seqT);
  unsigned short* kv1p   = (unsigned short*)(ws + o_kv1);
  unsigned short* qkv1p  = (unsigned short*)(ws + o_qkv1);
  unsigned short* expSp  = (unsigned short*)(ws + o_expS);

  hipMemsetAsync(ws + o_zp, 0, 4096, stream);
  hipMemsetAsync(ws + o_rs, 0, 4096 * 4, stream);

  // --- weight prep ---
  cvt_bf16<<<(256 * 1024 + 255) / 256, 256, 0, stream>>>(wk1, wKV1p, 256 * 1024);
  cvt_bf16<<<(512 * 1024 + 255) / 256, 256, 0, stream>>>(wv1, wKV1p + 256 * 1024, 512 * 1024);
  cvt_bf16<<<(256 * 1024 + 255) / 256, 256, 0, stream>>>(wqk1, wQKV1p, 256 * 1024);
  cvt_bf16<<<(512 * 1024 + 255) / 256, 256, 0, stream>>>(wqv1, wQKV1p + 256 * 1024, 512 * 1024);
  repack3<<<(256 * 2304 + 255) / 256, 256, 0, stream>>>(wk2, wK2p, 8, 256 * 2304);
  repack3<<<(256 * 2304 + 255) / 256, 256, 0, stream>>>(wqk2, wQK2p, 8, 256 * 2304);
  repack3<<<(512 * 4608 + 255) / 256, 256, 0, stream>>>(wv2, wV2p, 9, 512 * 4608);
  repack3<<<(512 * 4608 + 255) / 256, 256, 0, stream>>>(wqv2, wQV2p, 9, 512 * 4608);
  repack3<<<(512 * 9216 + 255) / 256, 256, 0, stream>>>(wb, wBp, 10, 512 * 9216);

  // --- input layout: fp32 NCHW -> bf16 [pos][c] ---
  nchw_to_cl<<<dim3(128, 32, 1), 256, 0, stream>>>(x, xTp, 1024, 4096);
  nchw_to_cl<<<dim3(128, 32, 4), 256, 0, stream>>>(seq, seqTp, 1024, 4096);

  if (SPLIT) {
    // kv1 (gemm256, fused): m=co 768, n=pos 16384 -> grid (64,3) = 192 blocks
    gemm256<G_CL, false, false, false><<<dim3(64, 3), 512, 0, stream>>>(
        wKV1p, seqTp, 1024, 1024, 1024, 0, 0, kv1p, 768, 0,
        gk1, bk1, gv1, bv1, 256, rs, zp);
    // qkv1 (gemm_k direct fused): 192 blocks
    gemm_k<EP_CL_BNR, false, false, false><<<dim3(32, 6), 256, 0, stream>>>(
        wQKV1p, xTp, 1024, 1024, 1024, 0, 0, qkv1p, 768, 0, 0,
        gqk1, bqk1, gqv1, bqv1, 256, rs, zp);
    // mk (gemm256): m=co 256, n=pos 16384
    {
      size_t plane = (size_t)16384 * 256;
      gemm256<G_PART, false, true, false><<<dim3(64, 1, zmk), 512, 0, stream>>>(
          wK2p, kv1p, 2304, 2304 / zmk, 768, 0, 8, partp, 256, plane,
          nullptr, nullptr, nullptr, nullptr, 0, rs, zp);
      int t4 = (int)(plane / 4);
      reduce_k<RED_BNR_BF16><<<(t4 + 255) / 256, 256, 0, stream>>>(
          partp, zmk, plane, 256, mkp, 256, 0, gk2, bk2, gk2, bk2, 256, rs, t4);
    }
    // qk: z=8 -> 512 blocks (gemm_k)
    {
      size_t plane = (size_t)4096 * 256;
      gemm_k<EP_PART, false, true, false><<<dim3(32, 2, 8), 256, 0, stream>>>(
          wQK2p, qkv1p, 2304, 288, 768, 0, 8, partp, 256, 0, plane,
          nullptr, nullptr, nullptr, nullptr, 0, rs, zp);
      int t4 = (int)(plane / 4);
      reduce_k<RED_BNR_BF16><<<(t4 + 255) / 256, 256, 0, stream>>>(
          partp, 8, plane, 256, qkp, 256, 0, gqk2, bqk2, gqk2, bqk2, 256, rs, t4);
    }
    // qv (gemm256): m=co 512, n=pos 4096
    {
      size_t plane = (size_t)4096 * 512;
      gemm256<G_PART, false, true, false><<<dim3(16, 2, zqv), 512, 0, stream>>>(
          wQV2p, qkv1p, 4608, 4608 / zqv, 768, 256, 9, partp, 512, plane,
          nullptr, nullptr, nullptr, nullptr, 0, rs, zp);
      int t4 = (int)(plane / 4);
      reduce_k<RED_BNR_BF16><<<(t4 + 255) / 256, 256, 0, stream>>>(
          partp, zqv, plane, 512, qvmp, 1024, 0, gqv2, bqv2, gqv2, bqv2, 512, rs, t4);
    }
    // mv (gemm256, CF): m=pos 16384, n=co 512
    {
      size_t plane = (size_t)512 * 16384;
      gemm256<G_PART, true, true, false><<<dim3(2, 64, zmv), 512, 0, stream>>>(
          wV2p, kv1p, 4608, 4608 / zmv, 768, 256, 9, partp, 16384, plane,
          nullptr, nullptr, nullptr, nullptr, 0, rs, zp);
      int t4 = (int)(plane / 4);
      reduce_k<RED_BNR_BF16_N><<<(t4 + 255) / 256, 256, 0, stream>>>(
          partp, zmv, plane, 16384, mvp, 16384, 0, gv2, bv2, nullptr, nullptr, 0, rs, t4);
    }
    // S-pass (gemm256 EXPSUM): m=kpos 16384, n=q 4096 -> 1024 blocks
    gemm256<G_EXPSUM, false, false, false><<<dim3(16, 64), 512, 0, stream>>>(
        mkp, qkp, 256, 256, 256, 0, 0, expSp, 4096, 0,
        nullptr, nullptr, nullptr, nullptr, 0, rs, zp);
    // PV (gemm256, XTILED): m=c 512, n=q 4096
    {
      size_t plane = (size_t)4096 * 512;
      gemm256<G_PART, false, false, true><<<dim3(16, 2, zpv), 512, 0, stream>>>(
          mvp, expSp, 16384, 16384 / zpv, 4096, 0, 0, partp, 512, plane,
          nullptr, nullptr, nullptr, nullptr, 0, rs, zp);
      int t4 = (int)(plane / 4);
      reduce_k<RED_PVDIV><<<(t4 + 255) / 256, 256, 0, stream>>>(
          partp, zpv, plane, 512, qvmp, 1024, 512, nullptr, nullptr, nullptr, nullptr, 0, rs, t4);
    }
    // final conv3x3 (gemm256, CF): m=pos 4096, n=co 512
    {
      size_t plane = (size_t)512 * 4096;
      gemm256<G_PART, true, true, false><<<dim3(2, 16, zfin), 512, 0, stream>>>(
          wBp, qvmp, 9216, 9216 / zfin, 1024, 0, 10, partp, 4096, plane,
          nullptr, nullptr, nullptr, nullptr, 0, rs, zp);
      int t4 = (int)(plane / 4);
      reduce_k<RED_BNR_F32><<<(t4 + 255) / 256, 256, 0, stream>>>(
          partp, zfin, plane, 4096, (float*)d_out, 4096, 0, gb, bb, gb, bb, 512, rs, t4);
    }
  } else {
    // fallback: direct kernels, row-major expS
    gemm_k<EP_CL_BNR, false, false, false><<<dim3(128, 6), 256, 0, stream>>>(
        wKV1p, seqTp, 1024, 1024, 1024, 0, 0, kv1p, 768, 0, 0,
        gk1, bk1, gv1, bv1, 256, rs, zp);
    gemm_k<EP_CL_BNR, false, false, false><<<dim3(32, 6), 256, 0, stream>>>(
        wQKV1p, xTp, 1024, 1024, 1024, 0, 0, qkv1p, 768, 0, 0,
        gqk1, bqk1, gqv1, bqv1, 256, rs, zp);
    gemm_k<EP_CL_BNR, false, true, false><<<dim3(128, 2), 256, 0, stream>>>(
        wK2p, kv1p, 2304, 2304, 768, 0, 8, mkp, 256, 0, 0,
        gk2, bk2, gk2, bk2, 256, rs, zp);
    gemm_k<EP_CL_BNR, false, true, false><<<dim3(32, 2), 256, 0, stream>>>(
        wQK2p, qkv1p, 2304, 2304, 768, 0, 8, qkp, 256, 0, 0,
        gqk2, bqk2, gqk2, bqk2, 256, rs, zp);
    gemm_k<EP_CL_BNR, false, true, false><<<dim3(32, 4), 256, 0, stream>>>(
        wQV2p, qkv1p, 4608, 4608, 768, 256, 9, qvmp, 1024, 0, 0,
        gqv2, bqv2, gqv2, bqv2, 512, rs, zp);
    gemm_k<EP_CF_BNR_BF16, true, true, false><<<dim3(4, 128), 256, 0, stream>>>(
        wV2p, kv1p, 4608, 4608, 768, 256, 9, mvp, 16384, 0, 0,
        gv2, bv2, gv2, bv2, 512, rs, zp);
    gemm_k<EP_EXPSUM, false, false, false><<<dim3(32, 128), 256, 0, stream>>>(
        mkp, qkp, 256, 256, 256, 0, 0, expSp, 16384, 0, 0,
        nullptr, nullptr, nullptr, nullptr, 0, rs, zp);
    gemm_k<EP_PVDIV, false, false, false><<<dim3(32, 4), 256, 0, stream>>>(
        mvp, expSp, 16384, 16384, 16384, 0, 0, qvmp, 1024, 512, 0,
        nullptr, nullptr, nullptr, nullptr, 0, rs, zp);
    gemm_k<EP_CF_BNR_F32, true, true, false><<<dim3(4, 32), 256, 0, stream>>>(
        wBp, qvmp, 9216, 9216, 1024, 0, 10, (float*)d_out, 4096, 0, 0,
        gb, bb, gb, bb, 512, rs, zp);
  }
}

// Round 13
// 554.239 us; speedup vs baseline: 6.1661x; 1.1418x over previous
//
#include <hip/hip_runtime.h>
#include <stdint.h>

// ---------------------------------------------------------------------------
// TMA head on MI355X. Round 13: VERBATIM REVERT to round 7 (557 µs, best
// verified). Rounds 8-12 (8-phase port, BK=32, bf16 partials, launch-bounds
// tightening, doubled z) all landed null/negative or broke correctness.
// gemm256: 256^2 x BK64, k-half staging, counted vmcnt(4), swizzled LDS
// (0 bank conflicts), setprio, XCD swizzle; fused {CL, EXPSUM} epilogues.
// ---------------------------------------------------------------------------

typedef short bf16x8 __attribute__((ext_vector_type(8)));
typedef float f32x4  __attribute__((ext_vector_type(4)));
typedef unsigned short u16x4 __attribute__((ext_vector_type(4)));

__device__ __forceinline__ unsigned short f2bf(float f) {
  union { float f; unsigned u; } x; x.f = f;
  unsigned r = x.u + 0x7FFFu + ((x.u >> 16) & 1u);   // RNE
  return (unsigned short)(r >> 16);
}

typedef const __attribute__((address_space(1))) char* as1cp;
typedef __attribute__((address_space(3))) char* as3p;

__device__ __forceinline__ void gl_lds16(const char* g, char* l) {
  __builtin_amdgcn_global_load_lds((as1cp)g, (as3p)l, 16, 0, 0);
}

enum { G_PART = 0, G_CL = 1, G_EXPSUM = 2 };

// ===========================================================================
// gemm256: 256x256 tile, BK=64, 512 threads (8 waves: 2 m-rows x 4 n-cols).
// Counted vmcnt(4) never drains in steady state; swizzled LDS panels
// (0 bank conflicts measured); setprio around the MFMA cluster; XCD-aware
// block swizzle (grids are multiples of 8).
// EP: G_PART  -> fp32 partials P[z][gn][gm]
//     G_CL    -> bf16 out[gn(pos)][gm(co)] with BN(gsplit)+ReLU fused
//     G_EXPSUM-> exp() to tiled expS [gm/32][Ostride=qtot][gm&31] + rowsum
// ===========================================================================
template<int EP, bool CF, bool CONV3, bool XTILED>
__global__ __launch_bounds__(512, 2) void gemm256(
    const unsigned short* __restrict__ Wp,   // [rows][K] bf16
    const unsigned short* __restrict__ Xp,   // activations (or tiled expS)
    int K, int Kc, int Xstride, int Xcoloff, int cin_log2,
    void* __restrict__ Op, int Ostride, size_t plane,
    const float* __restrict__ g1, const float* __restrict__ b1,
    const float* __restrict__ g2, const float* __restrict__ b2, int gsplit,
    float* __restrict__ rowsum, const char* __restrict__ zp)
{
  __shared__ short Ap[2][2][8192];   // [buf][khalf][1024 slots * 8 shorts]
  __shared__ short Bp[2][2][8192];
  const int tid = threadIdx.x;
  const int w = tid >> 6;
  const int l = tid & 63;
  const int wm_idx = w >> 2;     // 0..1
  const int wn_idx = w & 3;      // 0..3

  // XCD-aware bijective block swizzle (nwg % 8 == 0 for all call sites)
  int bx = blockIdx.x, by = blockIdx.y;
  {
    int nwg = gridDim.x * gridDim.y;
    if ((nwg & 7) == 0) {
      int id = bx + gridDim.x * by;
      id = (id & 7) * (nwg >> 3) + (id >> 3);
      bx = id % gridDim.x;
      by = id / gridDim.x;
    }
  }
  const int n0 = bx * 256;
  const int m0 = by * 256;
  const int wrow0 = CF ? n0 : m0;
  const int xrow0 = CF ? m0 : n0;

  // staging lane constants: g = (l&7)^(l>>3), rows grow0/grow0+16
  const int g = (l & 7) ^ (l >> 3);
  const int grow0 = w * 32 + 2 * (l >> 3) + (g >> 2);
  const int gc = g & 3;

  auto srcW = [&](int grow, int h, int k0) -> const char* {
    return (const char*)Wp +
           (((size_t)(wrow0 + grow)) * K + (size_t)(k0 + h * 32 + gc * 8)) * 2;
  };
  auto srcX = [&](int grow, int h, int k0) -> const char* {
    if constexpr (XTILED) {
      return (const char*)Xp + (size_t)((k0 + h * 32) >> 5) * ((size_t)Xstride * 64)
             + (size_t)(xrow0 + grow) * 64 + gc * 16;
    } else if constexpr (CONV3) {
      int e = k0 >> cin_log2;
      int ci0 = k0 & ((1 << cin_log2) - 1);
      int kh = e / 3, kw = e - kh * 3;
      int dpos = (kh - 1) * 64 + (kw - 1);
      int p = xrow0 + grow;
      int hw = p & 4095;
      int h2 = (hw >> 6) + kh - 1, w2 = (hw & 63) + kw - 1;
      return ((unsigned)h2 < 64u && (unsigned)w2 < 64u)
          ? (const char*)Xp + (((size_t)(p + dpos)) * Xstride
                               + (size_t)(Xcoloff + ci0 + h * 32 + gc * 8)) * 2
          : zp + gc * 16;
    } else {
      return (const char*)Xp + (((size_t)(xrow0 + grow)) * Xstride
                                + (size_t)(Xcoloff + k0 + h * 32 + gc * 8)) * 2;
    }
  };

  auto stage_half = [&](int b, int h, int k0) {
#pragma unroll
    for (int j = 0; j < 2; j++) {
      int grow = grow0 + j * 16;
      const char* sm = CF ? srcX(grow, h, k0) : srcW(grow, h, k0);
      gl_lds16(sm, (char*)&Ap[b][h][0] + w * 2048 + j * 1024);
    }
#pragma unroll
    for (int j = 0; j < 2; j++) {
      int grow = grow0 + j * 16;
      const char* sn = CF ? srcW(grow, h, k0) : srcX(grow, h, k0);
      gl_lds16(sn, (char*)&Bp[b][h][0] + w * 2048 + j * 1024);
    }
  };

  auto rd = [&](const short* base, int row, int ks) -> bf16x8 {
    int R = row >> 1;
    int sp = (((row & 1) << 2) | ks) ^ (R & 7);
    return *(const bf16x8*)(base + R * 64 + sp * 8);
  };

  f32x4 acc[8][4] = {};

  const int kb = blockIdx.z * Kc;
  const int NT = Kc >> 6;

  stage_half(0, 0, kb);
  stage_half(0, 1, kb);
  asm volatile("s_waitcnt vmcnt(4)" ::: "memory");
  __builtin_amdgcn_s_barrier();

  int buf = 0;
  for (int t = 0; t < NT; ++t) {
    int k0n = kb + (t + 1) * 64;
    bool pre = (t + 1 < NT);
#pragma unroll
    for (int h = 0; h < 2; ++h) {
      const short* Am = &Ap[buf][h][0];
      const short* Bm = &Bp[buf][h][0];
      bf16x8 af[8], bfv[4];
#pragma unroll
      for (int i = 0; i < 8; i++)
        af[i] = rd(Am, wm_idx * 128 + i * 16 + (l & 15), l >> 4);
#pragma unroll
      for (int j = 0; j < 4; j++)
        bfv[j] = rd(Bm, wn_idx * 64 + j * 16 + (l & 15), l >> 4);
      if (pre) stage_half(buf ^ 1, h, k0n);
      __builtin_amdgcn_s_setprio(1);
#pragma unroll
      for (int i = 0; i < 8; i++)
#pragma unroll
        for (int j = 0; j < 4; j++)
          acc[i][j] = __builtin_amdgcn_mfma_f32_16x16x32_bf16(af[i], bfv[j], acc[i][j], 0, 0, 0);
      __builtin_amdgcn_s_setprio(0);
      if (pre) asm volatile("s_waitcnt vmcnt(4)" ::: "memory");
      else     asm volatile("s_waitcnt vmcnt(0)" ::: "memory");
      __builtin_amdgcn_s_barrier();
    }
    buf ^= 1;
  }

  const int col = l & 15;
  const int rb2 = (l >> 4) << 2;

  if constexpr (EP == G_PART) {
    float* Pz = (float*)Op + (size_t)blockIdx.z * plane;
#pragma unroll
    for (int j = 0; j < 4; j++) {
      int gn = n0 + wn_idx * 64 + j * 16 + col;
#pragma unroll
      for (int i = 0; i < 8; i++) {
        int gm = m0 + wm_idx * 128 + i * 16 + rb2;
        *(f32x4*)(Pz + (size_t)gn * Ostride + gm) = acc[i][j];
      }
    }
  }
  if constexpr (EP == G_CL) {
    // out[gn(pos)][gm(co)] bf16, BN(gsplit on gm)+ReLU
#pragma unroll
    for (int i = 0; i < 8; i++) {
      int gm = m0 + wm_idx * 128 + i * 16 + rb2;
      const float* gp; const float* bp;
      if (gm < gsplit) { gp = g1 + gm; bp = b1 + gm; }
      else             { gp = g2 + (gm - gsplit); bp = b2 + (gm - gsplit); }
      float G[4], B[4];
#pragma unroll
      for (int r = 0; r < 4; r++) { G[r] = gp[r]; B[r] = bp[r]; }
#pragma unroll
      for (int j = 0; j < 4; j++) {
        int gn = n0 + wn_idx * 64 + j * 16 + col;
        f32x4 v = acc[i][j];
        u16x4 o;
#pragma unroll
        for (int r = 0; r < 4; r++) o[r] = f2bf(fmaxf(v[r] * G[r] + B[r], 0.f));
        *(u16x4*)((unsigned short*)Op + (size_t)gn * Ostride + gm) = o;
      }
    }
  }
  if constexpr (EP == G_EXPSUM) {
    // gm = kpos, gn = q; tiled expS [kpos/32][Ostride=qtot][kpos&31] + rowsum
#pragma unroll
    for (int j = 0; j < 4; j++) {
      int gn = n0 + wn_idx * 64 + j * 16 + col;   // q
      float s = 0.f;
#pragma unroll
      for (int i = 0; i < 8; i++) {
        int gm = m0 + wm_idx * 128 + i * 16 + rb2;  // kpos
        f32x4 v = acc[i][j];
        u16x4 o;
#pragma unroll
        for (int r = 0; r < 4; r++) { float e = __expf(v[r]); s += e; o[r] = f2bf(e); }
        *(u16x4*)((unsigned short*)Op + (size_t)(gm >> 5) * ((size_t)Ostride * 32)
                  + (size_t)gn * 32 + (gm & 31)) = o;
      }
      s += __shfl_xor(s, 16);
      s += __shfl_xor(s, 32);
      if (l < 16) atomicAdd(rowsum + gn, s);
    }
  }
}

enum { EP_CL_BNR = 0, EP_CF_BNR_BF16 = 1, EP_CF_BNR_F32 = 2, EP_EXPSUM = 3,
       EP_PVDIV = 4, EP_PART = 5 };

// 128x128 tile, BK=32, 256 threads (4 waves). Depth-2 pipeline.
template<int EP, bool CF, bool CONV3, bool XTILED>
__global__ __launch_bounds__(256) void gemm_k(
    const unsigned short* __restrict__ Wp,
    const unsigned short* __restrict__ Xp,
    int K, int Kc, int Xstride, int Xcoloff, int cin_log2,
    void* __restrict__ Op, int Ostride, int Ocoloff, size_t plane,
    const float* __restrict__ g1, const float* __restrict__ b1,
    const float* __restrict__ g2, const float* __restrict__ b2, int gsplit,
    float* __restrict__ rowsum, const char* __restrict__ zp)
{
  __shared__ short Wt[2][128 * 32];
  __shared__ short Xt[2][128 * 32];
  const int tid = threadIdx.x;
  const int w = tid >> 6;
  const int l = tid & 63;
  const int m0 = blockIdx.y * 128;
  const int n0 = blockIdx.x * 128;
  const int wrow0 = CF ? n0 : m0;
  const int xrow0 = CF ? m0 : n0;

  const int ch0 = w, ch1 = w + 4;
  const int sr0 = ch0 * 16 + (l >> 2);
  const int sr1 = ch1 * 16 + (l >> 2);
  const int kbp = (l & 3) << 4;
  const int kbl0 = kbp ^ ((sr0 & 3) << 4);
  const int kbl1 = kbp ^ ((sr1 & 3) << 4);

  const size_t wrb = (size_t)K * 2;
  const size_t xrb = (size_t)Xstride * 2;

  const int wm = (w >> 1) * 64;
  const int wn = (w & 1) * 64;

  const int k_begin = blockIdx.z * Kc;
  const int k_end = (k_begin + Kc < K) ? (k_begin + Kc) : K;

  auto stage = [&](int b, int k0) {
    int ci0 = k0, kh = 1, kw = 1, dpos = 0;
    if (CONV3) {
      int e = k0 >> cin_log2;
      ci0 = k0 & ((1 << cin_log2) - 1);
      kh = e / 3; kw = e - kh * 3;
      dpos = (kh - 1) * 64 + (kw - 1);
    }
    char* Wl = (char*)&Wt[b][0];
    char* Xl = (char*)&Xt[b][0];
    gl_lds16((const char*)Wp + (size_t)(wrow0 + sr0) * wrb + (size_t)k0 * 2 + kbl0,
             Wl + ch0 * 1024);
    gl_lds16((const char*)Wp + (size_t)(wrow0 + sr1) * wrb + (size_t)k0 * 2 + kbl1,
             Wl + ch1 * 1024);
    const char* xs0;
    const char* xs1;
    if constexpr (XTILED) {
      size_t kslab = (size_t)(k0 >> 5) * ((size_t)Xstride * 64);
      xs0 = (const char*)Xp + kslab + (size_t)(xrow0 + sr0) * 64 + kbl0;
      xs1 = (const char*)Xp + kslab + (size_t)(xrow0 + sr1) * 64 + kbl1;
    } else if constexpr (CONV3) {
      int p = xrow0 + sr0;
      int hw = p & 4095;
      int h2 = (hw >> 6) + kh - 1, w2 = (hw & 63) + kw - 1;
      xs0 = ((unsigned)h2 < 64u && (unsigned)w2 < 64u)
          ? (const char*)Xp + (size_t)(p + dpos) * xrb + (size_t)(Xcoloff + ci0) * 2 + kbl0
          : zp + kbl0;
      p = xrow0 + sr1;
      hw = p & 4095;
      h2 = (hw >> 6) + kh - 1; w2 = (hw & 63) + kw - 1;
      xs1 = ((unsigned)h2 < 64u && (unsigned)w2 < 64u)
          ? (const char*)Xp + (size_t)(p + dpos) * xrb + (size_t)(Xcoloff + ci0) * 2 + kbl1
          : zp + kbl1;
    } else {
      xs0 = (const char*)Xp + (size_t)(xrow0 + sr0) * xrb + (size_t)(Xcoloff + k0) * 2 + kbl0;
      xs1 = (const char*)Xp + (size_t)(xrow0 + sr1) * xrb + (size_t)(Xcoloff + k0) * 2 + kbl1;
    }
    gl_lds16(xs0, Xl + ch0 * 1024);
    gl_lds16(xs1, Xl + ch1 * 1024);
  };

  f32x4 acc[4][4] = {};

  int cur = 0;
  stage(0, k_begin);
  for (int k0 = k_begin; k0 < k_end; k0 += 32) {
    if (k0 + 32 < k_end) {
      stage(cur ^ 1, k0 + 32);
      asm volatile("s_waitcnt vmcnt(4)" ::: "memory");
    } else {
      asm volatile("s_waitcnt vmcnt(0)" ::: "memory");
    }
    __builtin_amdgcn_s_barrier();

    const short* Wb = &Wt[cur][0];
    const short* Xb = &Xt[cur][0];
    const short* At = CF ? Xb : Wb;
    const short* Bt = CF ? Wb : Xb;

    bf16x8 af[4], bfv[4];
#pragma unroll
    for (int i = 0; i < 4; i++) {
      int row = wm + i * 16 + (l & 15);
      int kb = ((l >> 4) << 4) ^ ((row & 3) << 4);
      af[i] = *(const bf16x8*)(At + row * 32 + (kb >> 1));
    }
#pragma unroll
    for (int j = 0; j < 4; j++) {
      int row = wn + j * 16 + (l & 15);
      int kb = ((l >> 4) << 4) ^ ((row & 3) << 4);
      bfv[j] = *(const bf16x8*)(Bt + row * 32 + (kb >> 1));
    }
#pragma unroll
    for (int i = 0; i < 4; i++)
#pragma unroll
      for (int j = 0; j < 4; j++)
        acc[i][j] = __builtin_amdgcn_mfma_f32_16x16x32_bf16(af[i], bfv[j], acc[i][j], 0, 0, 0);

    __builtin_amdgcn_s_barrier();
    cur ^= 1;
  }

  const int col = l & 15;
  const int rb = (l >> 4) << 2;

  if constexpr (EP == EP_PART) {
    float* P = (float*)Op + (size_t)blockIdx.z * plane;
#pragma unroll
    for (int j = 0; j < 4; j++) {
      int gn = n0 + wn + j * 16 + col;
#pragma unroll
      for (int i = 0; i < 4; i++) {
        int gm = m0 + wm + i * 16 + rb;
        *(f32x4*)(P + (size_t)gn * Ostride + gm) = acc[i][j];
      }
    }
  }
  if constexpr (EP == EP_CL_BNR) {
#pragma unroll
    for (int i = 0; i < 4; i++) {
      int gm = m0 + wm + i * 16 + rb;
      const float* gp; const float* bp;
      if (gm < gsplit) { gp = g1 + gm; bp = b1 + gm; }
      else             { gp = g2 + (gm - gsplit); bp = b2 + (gm - gsplit); }
      float G[4], B[4];
#pragma unroll
      for (int r = 0; r < 4; r++) { G[r] = gp[r]; B[r] = bp[r]; }
#pragma unroll
      for (int j = 0; j < 4; j++) {
        int gn = n0 + wn + j * 16 + col;
        f32x4 v = acc[i][j];
        u16x4 o;
#pragma unroll
        for (int r = 0; r < 4; r++) o[r] = f2bf(fmaxf(v[r] * G[r] + B[r], 0.f));
        *(u16x4*)((unsigned short*)Op + (size_t)gn * Ostride + Ocoloff + gm) = o;
      }
    }
  }
  if constexpr (EP == EP_CF_BNR_BF16 || EP == EP_CF_BNR_F32) {
#pragma unroll
    for (int j = 0; j < 4; j++) {
      int gn = n0 + wn + j * 16 + col;
      float G = (gn < gsplit) ? g1[gn] : g2[gn - gsplit];
      float Bv = (gn < gsplit) ? b1[gn] : b2[gn - gsplit];
#pragma unroll
      for (int i = 0; i < 4; i++) {
        int gm = m0 + wm + i * 16 + rb;
        f32x4 v = acc[i][j];
        if constexpr (EP == EP_CF_BNR_F32) {
          f32x4 o;
#pragma unroll
          for (int r = 0; r < 4; r++) o[r] = fmaxf(v[r] * G + Bv, 0.f);
          *(f32x4*)((float*)Op + (size_t)gn * Ostride + Ocoloff + gm) = o;
        } else {
          u16x4 o;
#pragma unroll
          for (int r = 0; r < 4; r++) o[r] = f2bf(fmaxf(v[r] * G + Bv, 0.f));
          *(u16x4*)((unsigned short*)Op + (size_t)gn * Ostride + Ocoloff + gm) = o;
        }
      }
    }
  }
  if constexpr (EP == EP_EXPSUM) {
#pragma unroll
    for (int j = 0; j < 4; j++) {
      int gn = n0 + wn + j * 16 + col;   // q
      float s = 0.f;
#pragma unroll
      for (int i = 0; i < 4; i++) {
        int gm = m0 + wm + i * 16 + rb;  // kpos
        f32x4 v = acc[i][j];
        u16x4 o;
#pragma unroll
        for (int r = 0; r < 4; r++) { float e = __expf(v[r]); s += e; o[r] = f2bf(e); }
        if (gsplit)
          *(u16x4*)((unsigned short*)Op + (size_t)(gm >> 5) * ((size_t)Ostride * 32)
                    + (size_t)gn * 32 + (gm & 31)) = o;
        else
          *(u16x4*)((unsigned short*)Op + (size_t)gn * Ostride + gm) = o;
      }
      s += __shfl_xor(s, 16);
      s += __shfl_xor(s, 32);
      if (l < 16) atomicAdd(rowsum + gn, s);
    }
  }
  if constexpr (EP == EP_PVDIV) {
#pragma unroll
    for (int j = 0; j < 4; j++) {
      int gn = n0 + wn + j * 16 + col;   // q
      float inv = 1.0f / rowsum[gn];
#pragma unroll
      for (int i = 0; i < 4; i++) {
        int gm = m0 + wm + i * 16 + rb;  // c
        f32x4 v = acc[i][j];
        u16x4 o;
#pragma unroll
        for (int r = 0; r < 4; r++) o[r] = f2bf(v[r] * inv);
        *(u16x4*)((unsigned short*)Op + (size_t)gn * Ostride + Ocoloff + gm) = o;
      }
    }
  }
}

// ---- split-K reduce: sum Z fp32 planes, apply epilogue ----
enum { RED_BNR_BF16 = 0, RED_PVDIV = 1, RED_BNR_F32 = 2, RED_BNR_BF16_N = 3 };

template<int MODE>
__global__ __launch_bounds__(256) void reduce_k(
    const float* __restrict__ P, int Z, size_t plane, int Cdim,
    void* __restrict__ out, int Ostride, int Ocoloff,
    const float* __restrict__ g1, const float* __restrict__ b1,
    const float* __restrict__ g2, const float* __restrict__ b2, int gsplit,
    const float* __restrict__ rowsum, int total4)
{
  int t = blockIdx.x * 256 + threadIdx.x;
  if (t >= total4) return;
  size_t base = (size_t)t * 4;
  int n = (int)(base / (size_t)Cdim);
  int c = (int)(base % (size_t)Cdim);
  f32x4 s = *(const f32x4*)(P + base);
  for (int z = 1; z < Z; z++) {
    f32x4 v = *(const f32x4*)(P + (size_t)z * plane + base);
    s += v;
  }
  if constexpr (MODE == RED_BNR_BF16) {
    u16x4 o;
#pragma unroll
    for (int r = 0; r < 4; r++) {
      int ch = c + r;
      float G = (ch < gsplit) ? g1[ch] : g2[ch - gsplit];
      float B = (ch < gsplit) ? b1[ch] : b2[ch - gsplit];
      o[r] = f2bf(fmaxf(s[r] * G + B, 0.f));
    }
    *(u16x4*)((unsigned short*)out + (size_t)n * Ostride + Ocoloff + c) = o;
  }
  if constexpr (MODE == RED_BNR_BF16_N) {
    float G = g1[n], B = b1[n];
    u16x4 o;
#pragma unroll
    for (int r = 0; r < 4; r++) o[r] = f2bf(fmaxf(s[r] * G + B, 0.f));
    *(u16x4*)((unsigned short*)out + (size_t)n * Ostride + Ocoloff + c) = o;
  }
  if constexpr (MODE == RED_PVDIV) {
    float inv = 1.0f / rowsum[n];
    u16x4 o;
#pragma unroll
    for (int r = 0; r < 4; r++) o[r] = f2bf(s[r] * inv);
    *(u16x4*)((unsigned short*)out + (size_t)n * Ostride + Ocoloff + c) = o;
  }
  if constexpr (MODE == RED_BNR_F32) {
    float G = g1[n], B = b1[n];
    f32x4 o;
#pragma unroll
    for (int r = 0; r < 4; r++) o[r] = fmaxf(s[r] * G + B, 0.f);
    *(f32x4*)((float*)out + (size_t)n * Ostride + c) = o;
  }
}

// fp32 NCHW frame -> bf16 channel-last [pos][c]
__global__ __launch_bounds__(256) void nchw_to_cl(const float* __restrict__ src,
                                                  unsigned short* __restrict__ dst,
                                                  int C, int P) {
  __shared__ float t[32][33];
  int f = blockIdx.z;
  src += (size_t)f * C * P;
  dst += (size_t)f * C * P;
  int p0 = blockIdx.x * 32, c0 = blockIdx.y * 32;
  int a = threadIdx.x & 31, b = threadIdx.x >> 5;
#pragma unroll
  for (int k = 0; k < 4; k++)
    t[b + 8 * k][a] = src[(size_t)(c0 + b + 8 * k) * P + p0 + a];
  __syncthreads();
#pragma unroll
  for (int k = 0; k < 4; k++)
    dst[(size_t)(p0 + b + 8 * k) * C + c0 + a] = f2bf(t[a][b + 8 * k]);
}

__global__ __launch_bounds__(256) void cvt_bf16(const float* __restrict__ s,
                                                unsigned short* __restrict__ d, int n) {
  int i = blockIdx.x * 256 + threadIdx.x;
  if (i < n) d[i] = f2bf(s[i]);
}

// [co][ci][3][3] fp32 -> [co][kh][kw][ci] bf16
__global__ __launch_bounds__(256) void repack3(const float* __restrict__ s,
                                               unsigned short* __restrict__ d,
                                               int ci_log2, int n) {
  int i = blockIdx.x * 256 + threadIdx.x;
  if (i >= n) return;
  int Ci = 1 << ci_log2;
  int ci = i & (Ci - 1);
  int t = i >> ci_log2;
  int e = t % 9;
  int co = t / 9;
  d[i] = f2bf(s[((size_t)co * Ci + ci) * 9 + e]);
}

__global__ __launch_bounds__(256) void fillf(float* p, float v, int n) {
  int i = blockIdx.x * 256 + threadIdx.x;
  if (i < n) p[i] = v;
}

extern "C" void kernel_launch(void* const* d_in, const int* in_sizes, int n_in,
                              void* d_out, int out_size, void* d_ws, size_t ws_size,
                              hipStream_t stream) {
  (void)in_sizes; (void)n_in;
  const float* x    = (const float*)d_in[0];
  const float* seq  = (const float*)d_in[1];
  const float* wk1  = (const float*)d_in[2];
  const float* gk1  = (const float*)d_in[3];
  const float* bk1  = (const float*)d_in[4];
  const float* wk2  = (const float*)d_in[5];
  const float* gk2  = (const float*)d_in[6];
  const float* bk2  = (const float*)d_in[7];
  const float* wv1  = (const float*)d_in[8];
  const float* gv1  = (const float*)d_in[9];
  const float* bv1  = (const float*)d_in[10];
  const float* wv2  = (const float*)d_in[11];
  const float* gv2  = (const float*)d_in[12];
  const float* bv2  = (const float*)d_in[13];
  const float* wqk1 = (const float*)d_in[14];
  const float* gqk1 = (const float*)d_in[15];
  const float* bqk1 = (const float*)d_in[16];
  const float* wqk2 = (const float*)d_in[17];
  const float* gqk2 = (const float*)d_in[18];
  const float* bqk2 = (const float*)d_in[19];
  const float* wqv1 = (const float*)d_in[20];
  const float* gqv1 = (const float*)d_in[21];
  const float* bqv1 = (const float*)d_in[22];
  const float* wqv2 = (const float*)d_in[23];
  const float* gqv2 = (const float*)d_in[24];
  const float* bqv2 = (const float*)d_in[25];
  const float* wb   = (const float*)d_in[26];
  const float* gb   = (const float*)d_in[27];
  const float* bb   = (const float*)d_in[28];

  char* ws = (char*)d_ws;
  size_t off = 0;
  auto alloc = [&](size_t bytes) { size_t o = off; off += (bytes + 255) & ~(size_t)255; return o; };
  size_t o_zp    = alloc(4096);
  size_t o_rs    = alloc(4096 * 4);
  size_t o_wKV1  = alloc((size_t)768 * 1024 * 2);
  size_t o_wQKV1 = alloc((size_t)768 * 1024 * 2);
  size_t o_wK2   = alloc((size_t)256 * 2304 * 2);
  size_t o_wQK2  = alloc((size_t)256 * 2304 * 2);
  size_t o_wV2   = alloc((size_t)512 * 4608 * 2);
  size_t o_wQV2  = alloc((size_t)512 * 4608 * 2);
  size_t o_wB    = alloc((size_t)512 * 9216 * 2);
  size_t o_mk    = alloc((size_t)16384 * 256 * 2);
  size_t o_mv    = alloc((size_t)512 * 16384 * 2);
  size_t o_qk    = alloc((size_t)4096 * 256 * 2);
  size_t o_qvm   = alloc((size_t)4096 * 1024 * 2);
  size_t o_part  = alloc((size_t)8 * 4096 * 512 * 4);   // 64MB split-K partials
  size_t o_vol   = off;
  size_t o_xT    = o_vol;
  size_t o_seqT  = o_xT + (size_t)4096 * 1024 * 2;
  size_t o_kv1   = o_seqT + (size_t)4 * 4096 * 1024 * 2;
  size_t o_qkv1  = o_kv1 + (size_t)16384 * 768 * 2;
  size_t end1    = o_qkv1 + (size_t)4096 * 768 * 2;
  size_t o_expS  = o_vol;                       // overlays dead early buffers
  size_t end2    = o_expS + (size_t)4096 * 16384 * 2;
  size_t need    = end1 > end2 ? end1 : end2;

  bool SPLIT = ws_size >= need;
  if (!SPLIT) {
    size_t save = o_part;
    o_vol  = save;
    o_xT   = o_vol;
    o_seqT = o_xT + (size_t)4096 * 1024 * 2;
    o_kv1  = o_seqT + (size_t)4 * 4096 * 1024 * 2;
    o_qkv1 = o_kv1 + (size_t)16384 * 768 * 2;
    end1   = o_qkv1 + (size_t)4096 * 768 * 2;
    o_expS = o_vol;
    end2   = o_expS + (size_t)4096 * 16384 * 2;
    need   = end1 > end2 ? end1 : end2;
    if (ws_size < need) {
      fillf<<<(out_size + 255) / 256, 256, 0, stream>>>((float*)d_out, 12345.0f, out_size);
      return;
    }
  }

  const char* zp = ws + o_zp;
  float* rs = (float*)(ws + o_rs);
  unsigned short* wKV1p  = (unsigned short*)(ws + o_wKV1);
  unsigned short* wQKV1p = (unsigned short*)(ws + o_wQKV1);
  unsigned short* wK2p   = (unsigned short*)(ws + o_wK2);
  unsigned short* wQK2p  = (unsigned short*)(ws + o_wQK2);
  unsigned short* wV2p   = (unsigned short*)(ws + o_wV2);
  unsigned short* wQV2p  = (unsigned short*)(ws + o_wQV2);
  unsigned short* wBp    = (unsigned short*)(ws + o_wB);
  unsigned short* mkp    = (unsigned short*)(ws + o_mk);
  unsigned short* mvp    = (unsigned short*)(ws + o_mv);
  unsigned short* qkp    = (unsigned short*)(ws + o_qk);
  unsigned short* qvmp   = (unsigned short*)(ws + o_qvm);
  float* partp           = (float*)(ws + o_part);
  unsigned short* xTp    = (unsigned short*)(ws + o_xT);
  unsigned short* seqTp  = (unsigned short*)(ws + o_seqT);
  unsigned short* kv1p   = (unsigned short*)(ws + o_kv1);
  unsigned short* qkv1p  = (unsigned short*)(ws + o_qkv1);
  unsigned short* expSp  = (unsigned short*)(ws + o_expS);

  hipMemsetAsync(ws + o_zp, 0, 4096, stream);
  hipMemsetAsync(ws + o_rs, 0, 4096 * 4, stream);

  // --- weight prep ---
  cvt_bf16<<<(256 * 1024 + 255) / 256, 256, 0, stream>>>(wk1, wKV1p, 256 * 1024);
  cvt_bf16<<<(512 * 1024 + 255) / 256, 256, 0, stream>>>(wv1, wKV1p + 256 * 1024, 512 * 1024);
  cvt_bf16<<<(256 * 1024 + 255) / 256, 256, 0, stream>>>(wqk1, wQKV1p, 256 * 1024);
  cvt_bf16<<<(512 * 1024 + 255) / 256, 256, 0, stream>>>(wqv1, wQKV1p + 256 * 1024, 512 * 1024);
  repack3<<<(256 * 2304 + 255) / 256, 256, 0, stream>>>(wk2, wK2p, 8, 256 * 2304);
  repack3<<<(256 * 2304 + 255) / 256, 256, 0, stream>>>(wqk2, wQK2p, 8, 256 * 2304);
  repack3<<<(512 * 4608 + 255) / 256, 256, 0, stream>>>(wv2, wV2p, 9, 512 * 4608);
  repack3<<<(512 * 4608 + 255) / 256, 256, 0, stream>>>(wqv2, wQV2p, 9, 512 * 4608);
  repack3<<<(512 * 9216 + 255) / 256, 256, 0, stream>>>(wb, wBp, 10, 512 * 9216);

  // --- input layout: fp32 NCHW -> bf16 [pos][c] ---
  nchw_to_cl<<<dim3(128, 32, 1), 256, 0, stream>>>(x, xTp, 1024, 4096);
  nchw_to_cl<<<dim3(128, 32, 4), 256, 0, stream>>>(seq, seqTp, 1024, 4096);

  if (SPLIT) {
    // kv1 (gemm256, fused): m=co 768, n=pos 16384 -> grid (64,3) = 192 blocks
    gemm256<G_CL, false, false, false><<<dim3(64, 3), 512, 0, stream>>>(
        wKV1p, seqTp, 1024, 1024, 1024, 0, 0, kv1p, 768, 0,
        gk1, bk1, gv1, bv1, 256, rs, zp);
    // qkv1 (gemm_k direct fused): 192 blocks
    gemm_k<EP_CL_BNR, false, false, false><<<dim3(32, 6), 256, 0, stream>>>(
        wQKV1p, xTp, 1024, 1024, 1024, 0, 0, qkv1p, 768, 0, 0,
        gqk1, bqk1, gqv1, bqv1, 256, rs, zp);
    // mk (gemm256): m=co 256, n=pos 16384, z=4 -> 256 blocks
    {
      size_t plane = (size_t)16384 * 256;
      gemm256<G_PART, false, true, false><<<dim3(64, 1, 4), 512, 0, stream>>>(
          wK2p, kv1p, 2304, 576, 768, 0, 8, partp, 256, plane,
          nullptr, nullptr, nullptr, nullptr, 0, rs, zp);
      int t4 = (int)(plane / 4);
      reduce_k<RED_BNR_BF16><<<(t4 + 255) / 256, 256, 0, stream>>>(
          partp, 4, plane, 256, mkp, 256, 0, gk2, bk2, gk2, bk2, 256, rs, t4);
    }
    // qk: z=8 -> 512 blocks (gemm_k)
    {
      size_t plane = (size_t)4096 * 256;
      gemm_k<EP_PART, false, true, false><<<dim3(32, 2, 8), 256, 0, stream>>>(
          wQK2p, qkv1p, 2304, 288, 768, 0, 8, partp, 256, 0, plane,
          nullptr, nullptr, nullptr, nullptr, 0, rs, zp);
      int t4 = (int)(plane / 4);
      reduce_k<RED_BNR_BF16><<<(t4 + 255) / 256, 256, 0, stream>>>(
          partp, 8, plane, 256, qkp, 256, 0, gqk2, bqk2, gqk2, bqk2, 256, rs, t4);
    }
    // qv (gemm256): m=co 512, n=pos 4096, z=8 -> 256 blocks
    {
      size_t plane = (size_t)4096 * 512;
      gemm256<G_PART, false, true, false><<<dim3(16, 2, 8), 512, 0, stream>>>(
          wQV2p, qkv1p, 4608, 576, 768, 256, 9, partp, 512, plane,
          nullptr, nullptr, nullptr, nullptr, 0, rs, zp);
      int t4 = (int)(plane / 4);
      reduce_k<RED_BNR_BF16><<<(t4 + 255) / 256, 256, 0, stream>>>(
          partp, 8, plane, 512, qvmp, 1024, 0, gqv2, bqv2, gqv2, bqv2, 512, rs, t4);
    }
    // mv (gemm256, CF): m=pos 16384, n=co 512, z=2 -> 256 blocks
    {
      size_t plane = (size_t)512 * 16384;
      gemm256<G_PART, true, true, false><<<dim3(2, 64, 2), 512, 0, stream>>>(
          wV2p, kv1p, 4608, 2304, 768, 256, 9, partp, 16384, plane,
          nullptr, nullptr, nullptr, nullptr, 0, rs, zp);
      int t4 = (int)(plane / 4);
      reduce_k<RED_BNR_BF16_N><<<(t4 + 255) / 256, 256, 0, stream>>>(
          partp, 2, plane, 16384, mvp, 16384, 0, gv2, bv2, nullptr, nullptr, 0, rs, t4);
    }
    // S-pass (gemm256 EXPSUM): m=kpos 16384, n=q 4096 -> grid (16,64) = 1024
    gemm256<G_EXPSUM, false, false, false><<<dim3(16, 64), 512, 0, stream>>>(
        mkp, qkp, 256, 256, 256, 0, 0, expSp, 4096, 0,
        nullptr, nullptr, nullptr, nullptr, 0, rs, zp);
    // PV (gemm256, XTILED): m=c 512, n=q 4096, z=8 -> 256 blocks
    {
      size_t plane = (size_t)4096 * 512;
      gemm256<G_PART, false, false, true><<<dim3(16, 2, 8), 512, 0, stream>>>(
          mvp, expSp, 16384, 2048, 4096, 0, 0, partp, 512, plane,
          nullptr, nullptr, nullptr, nullptr, 0, rs, zp);
      int t4 = (int)(plane / 4);
      reduce_k<RED_PVDIV><<<(t4 + 255) / 256, 256, 0, stream>>>(
          partp, 8, plane, 512, qvmp, 1024, 512, nullptr, nullptr, nullptr, nullptr, 0, rs, t4);
    }
    // final conv3x3 (gemm256, CF): m=pos 4096, n=co 512, z=8
    {
      size_t plane = (size_t)512 * 4096;
      gemm256<G_PART, true, true, false><<<dim3(2, 16, 8), 512, 0, stream>>>(
          wBp, qvmp, 9216, 1152, 1024, 0, 10, partp, 4096, plane,
          nullptr, nullptr, nullptr, nullptr, 0, rs, zp);
      int t4 = (int)(plane / 4);
      reduce_k<RED_BNR_F32><<<(t4 + 255) / 256, 256, 0, stream>>>(
          partp, 8, plane, 4096, (float*)d_out, 4096, 0, gb, bb, gb, bb, 512, rs, t4);
    }
  } else {
    // fallback: direct kernels, row-major expS
    gemm_k<EP_CL_BNR, false, false, false><<<dim3(128, 6), 256, 0, stream>>>(
        wKV1p, seqTp, 1024, 1024, 1024, 0, 0, kv1p, 768, 0, 0,
        gk1, bk1, gv1, bv1, 256, rs, zp);
    gemm_k<EP_CL_BNR, false, false, false><<<dim3(32, 6), 256, 0, stream>>>(
        wQKV1p, xTp, 1024, 1024, 1024, 0, 0, qkv1p, 768, 0, 0,
        gqk1, bqk1, gqv1, bqv1, 256, rs, zp);
    gemm_k<EP_CL_BNR, false, true, false><<<dim3(128, 2), 256, 0, stream>>>(
        wK2p, kv1p, 2304, 2304, 768, 0, 8, mkp, 256, 0, 0,
        gk2, bk2, gk2, bk2, 256, rs, zp);
    gemm_k<EP_CL_BNR, false, true, false><<<dim3(32, 2), 256, 0, stream>>>(
        wQK2p, qkv1p, 2304, 2304, 768, 0, 8, qkp, 256, 0, 0,
        gqk2, bqk2, gqk2, bqk2, 256, rs, zp);
    gemm_k<EP_CL_BNR, false, true, false><<<dim3(32, 4), 256, 0, stream>>>(
        wQV2p, qkv1p, 4608, 4608, 768, 256, 9, qvmp, 1024, 0, 0,
        gqv2, bqv2, gqv2, bqv2, 512, rs, zp);
    gemm_k<EP_CF_BNR_BF16, true, true, false><<<dim3(4, 128), 256, 0, stream>>>(
        wV2p, kv1p, 4608, 4608, 768, 256, 9, mvp, 16384, 0, 0,
        gv2, bv2, gv2, bv2, 512, rs, zp);
    gemm_k<EP_EXPSUM, false, false, false><<<dim3(32, 128), 256, 0, stream>>>(
        mkp, qkp, 256, 256, 256, 0, 0, expSp, 16384, 0, 0,
        nullptr, nullptr, nullptr, nullptr, 0, rs, zp);
    gemm_k<EP_PVDIV, false, false, false><<<dim3(32, 4), 256, 0, stream>>>(
        mvp, expSp, 16384, 16384, 16384, 0, 0, qvmp, 1024, 512, 0,
        nullptr, nullptr, nullptr, nullptr, 0, rs, zp);
    gemm_k<EP_CF_BNR_F32, true, true, false><<<dim3(4, 32), 256, 0, stream>>>(
        wBp, qvmp, 9216, 9216, 1024, 0, 10, (float*)d_out, 4096, 0, 0,
        gb, bb, gb, bb, 512, rs, zp);
  }
}